// Round 4
// baseline (1488.149 us; speedup 1.0000x reference)
//
#include <hip/hip_runtime.h>
#include <hip/hip_cooperative_groups.h>
#include <cstdint>

namespace cg = cooperative_groups;

#define B_   512
#define I_   2560
#define H_   512
#define E_   300
#define EW   320     // padded emb width
#define V_   8000
#define VPAD 8064    // 63 * 128
#define T_   16
#define G4H  2048
#define SOS_ 2

typedef _Float16 f16;
typedef _Float16 f16x8 __attribute__((ext_vector_type(8)));
typedef _Float16 f16x4 __attribute__((ext_vector_type(4)));
typedef float    f32x4 __attribute__((ext_vector_type(4)));

__device__ __forceinline__ float sigmoidf_(float x) {
    return 1.0f / (1.0f + __expf(-x));
}

__device__ __forceinline__ void gload16(const void* g, void* l) {
    __builtin_amdgcn_global_load_lds(
        (const __attribute__((address_space(1))) void*)g,
        (__attribute__((address_space(3))) void*)l,
        16, 0, 0);
}

// ---------------------------------------------------------------------------
// Generic MFMA f16 GEMM (m97 structure, verified rounds 2-3): 128x128 tile,
// BK=32, 4 waves 2x2, linear LDS + global_load_lds w=16.
// ---------------------------------------------------------------------------
__global__ __launch_bounds__(256)
void gemm_mfma(const f16* __restrict__ A, int lda,
               const f16* __restrict__ Bw, int ldb,
               float* __restrict__ C, int ldc,
               int K, int Nvalid,
               const float* __restrict__ bias1,
               const float* __restrict__ bias2)
{
    __shared__ f16 As[128][32];
    __shared__ f16 Bs[128][32];

    const int tid  = threadIdx.x;
    const int w    = tid >> 6;
    const int lane = tid & 63;
    const int bm   = blockIdx.x * 128;
    const int bn   = blockIdx.y * 128;
    const int wr   = w >> 1;
    const int wc   = w & 1;

    const int srow = lane >> 2;
    const int skel = (lane & 3) * 8;

    const f16* Ag0 = A  + (size_t)(bm + w*32 +      srow) * lda + skel;
    const f16* Ag1 = A  + (size_t)(bm + w*32 + 16 + srow) * lda + skel;
    const f16* Bg0 = Bw + (size_t)(bn + w*32 +      srow) * ldb + skel;
    const f16* Bg1 = Bw + (size_t)(bn + w*32 + 16 + srow) * ldb + skel;
    f16* Al0 = &As[w*32     ][0];
    f16* Al1 = &As[w*32 + 16][0];
    f16* Bl0 = &Bs[w*32     ][0];
    f16* Bl1 = &Bs[w*32 + 16][0];

    const int frow = lane & 15;
    const int fk   = (lane >> 4) * 8;

    f32x4 acc[4][4] = {};

    for (int k0 = 0; k0 < K; k0 += 32) {
        gload16(Ag0 + k0, Al0);
        gload16(Ag1 + k0, Al1);
        gload16(Bg0 + k0, Bl0);
        gload16(Bg1 + k0, Bl1);
        __syncthreads();

        f16x8 af[4], bf[4];
        #pragma unroll
        for (int m = 0; m < 4; ++m)
            af[m] = *reinterpret_cast<const f16x8*>(&As[wr*64 + m*16 + frow][fk]);
        #pragma unroll
        for (int n = 0; n < 4; ++n)
            bf[n] = *reinterpret_cast<const f16x8*>(&Bs[wc*64 + n*16 + frow][fk]);

        #pragma unroll
        for (int m = 0; m < 4; ++m)
            #pragma unroll
            for (int n = 0; n < 4; ++n)
                acc[m][n] = __builtin_amdgcn_mfma_f32_16x16x32_f16(
                    af[m], bf[n], acc[m][n], 0, 0, 0);

        __syncthreads();
    }

    const int rowb = bm + wr*64 + (lane >> 4) * 4;
    #pragma unroll
    for (int n = 0; n < 4; ++n) {
        const int col = bn + wc*64 + n*16 + frow;
        if (col >= Nvalid) continue;
        float badd = 0.0f;
        if (bias1) badd += bias1[col];
        if (bias2) badd += bias2[col];
        #pragma unroll
        for (int m = 0; m < 4; ++m) {
            const int r0 = rowb + m*16;
            #pragma unroll
            for (int r = 0; r < 4; ++r)
                C[(size_t)(r0 + r) * ldc + col] = acc[m][n][r] + badd;
        }
    }
}

// ---------------------------------------------------------------------------
// Persistent cooperative recurrent kernel.
// 256 blocks x 256 threads; block b owns rows [bm,bm+64) x packed cols
// [bn,bn+64) of both layer GEMMs for all 16 steps. Packed col layout:
// col = (h>>4)*64 + g*16 + (h&15)  (gate order i,f,g,o), so a 64-col tile
// holds complete 16-h x 4-gate groups. c-state lives in registers.
// ---------------------------------------------------------------------------
struct PArgs {
    const f16*  embAll;   // [16][512][320]
    const f16*  W0p;      // [2048][832]
    const f16*  W1p;      // [2048][1024]
    const float* ctxg;    // [512][2048] packed, includes b_ih0+b_hh0
    const float* b1p;     // [2048] packed, b_ih1+b_hh1
    const float* ctxcc;   // [512][1024] (cols 512.. = cell init, pre-bias)
    const float* b_cell;
    f16* h0a; f16* h0b;
    f16* h1a; f16* h1b;
    f16* hs;              // [512*16][512], row = b*16 + t
};

template<int K, bool HAS_CADD, bool HAS_BVEC>
__device__ __forceinline__ void gemm_cell(
    const f16* __restrict__ Ap1, int lda1,
    const f16* __restrict__ Ap2, int lda2,
    const f16* __restrict__ Wp,
    const float* __restrict__ Cadd,
    const float* __restrict__ bvec,
    float creg[4],
    f16* __restrict__ hout, f16* __restrict__ hout2,
    int bm, int bn, char* smem, int tid)
{
    const int w    = tid >> 6;
    const int lane = tid & 63;
    const int wr   = w >> 1, wc = w & 1;
    const int frow = lane & 15, hi = lane >> 4;
    const int sw    = (frow & 7) << 4;
    const int srow8 = lane >> 3;
    const int ksb   = ((((lane & 7) * 16) ^ (srow8 << 4)) >> 1);

    f32x4 acc[2][2] = {};

    auto stage = [&](int bsel, int kt) {
        const int k0 = kt << 6;
        #pragma unroll
        for (int j = 0; j < 2; ++j) {
            const int row = w*16 + j*8 + srow8;
            const f16* srcA = (k0 < 512)
                ? Ap1 + (size_t)(bm + row) * lda1 + k0 + ksb
                : Ap2 + (size_t)(bm + row) * lda2 + (k0 - 512) + ksb;
            gload16(srcA, smem + bsel*8192 + (w*2 + j)*1024 + lane*16);
            gload16(Wp + (size_t)(bn + row) * K + k0 + ksb,
                    smem + 16384 + bsel*8192 + (w*2 + j)*1024 + lane*16);
        }
    };

    auto compute = [&](int bsel) {
        const char* As = smem + bsel*8192;
        const char* Bs = smem + 16384 + bsel*8192;
        #pragma unroll
        for (int ks = 0; ks < 2; ++ks) {
            const int cb = (ks*64 + hi*16) ^ sw;
            f16x8 af[2], bf[2];
            #pragma unroll
            for (int m = 0; m < 2; ++m)
                af[m] = *reinterpret_cast<const f16x8*>(As + (wr*32 + m*16 + frow)*128 + cb);
            #pragma unroll
            for (int n = 0; n < 2; ++n)
                bf[n] = *reinterpret_cast<const f16x8*>(Bs + (wc*32 + n*16 + frow)*128 + cb);
            #pragma unroll
            for (int m = 0; m < 2; ++m)
                #pragma unroll
                for (int n = 0; n < 2; ++n)
                    acc[m][n] = __builtin_amdgcn_mfma_f32_16x16x32_f16(
                        af[m], bf[n], acc[m][n], 0, 0, 0);
        }
    };

    constexpr int NT = K >> 6;
    stage(0, 0);
    __syncthreads();
    int buf = 0;
    #pragma unroll
    for (int kt = 0; kt + 1 < NT; ++kt) {
        stage(buf ^ 1, kt + 1);
        compute(buf);
        __syncthreads();
        buf ^= 1;
    }
    compute(buf);
    __syncthreads();                       // LDS reads done; safe to alias gs

    // acc -> gates LDS (+ Cadd)
    float* gs = (float*)smem;              // [64][68]
    #pragma unroll
    for (int m = 0; m < 2; ++m) {
        const int row = wr*32 + m*16 + hi*4;
        #pragma unroll
        for (int n = 0; n < 2; ++n) {
            const int col = wc*32 + n*16 + frow;
            #pragma unroll
            for (int r = 0; r < 4; ++r) {
                float v = acc[m][n][r];
                if (HAS_CADD) v += Cadd[(size_t)(bm + row + r) * G4H + bn + col];
                gs[(row + r)*68 + col] = v;
            }
        }
    }
    __syncthreads();

    // cell: thread -> h-lane hp, rows rr*4..rr*4+3
    const int hp = tid & 15, rr = tid >> 4;
    const int hg = (bn >> 2) + hp;         // global h index
    float bi[4] = {0.f, 0.f, 0.f, 0.f};
    if (HAS_BVEC) {
        #pragma unroll
        for (int g = 0; g < 4; ++g) bi[g] = bvec[bn + g*16 + hp];
    }
    #pragma unroll
    for (int i = 0; i < 4; ++i) {
        const int r = rr*4 + i;
        const int b = bm + r;
        const float gi = gs[r*68 +      hp] + bi[0];
        const float gf = gs[r*68 + 16 + hp] + bi[1];
        const float gc = gs[r*68 + 32 + hp] + bi[2];
        const float go = gs[r*68 + 48 + hp] + bi[3];
        const float cn = sigmoidf_(gf) * creg[i] + sigmoidf_(gi) * tanhf(gc);
        const float hn = sigmoidf_(go) * tanhf(cn);
        creg[i] = cn;
        hout[(size_t)b * H_ + hg] = (f16)hn;
        if (hout2) hout2[(size_t)b * (T_ * H_) + hg] = (f16)hn;
    }
}

__global__ __launch_bounds__(256, 1)
void lstm_persist(PArgs a)
{
    __shared__ uint4 smem4[32768 / 16];
    char* smem = (char*)smem4;

    cg::grid_group grid = cg::this_grid();
    const int tid = threadIdx.x;
    const int blk = blockIdx.x;
    const int i0 = blk >> 5, j0 = blk & 31;
    const int bm = i0 * 64, bn = j0 * 64;
    const int hp = tid & 15, rr = tid >> 4;
    const int hg = j0 * 16 + hp;

    float c0reg[4], c1reg[4];
    #pragma unroll
    for (int i = 0; i < 4; ++i) {
        const int b = bm + rr*4 + i;
        const float cc = a.ctxcc[(size_t)b * 1024 + 512 + hg] + a.b_cell[hg];
        c0reg[i] = cc;
        c1reg[i] = cc;
    }

    f16* h0bufs[2] = { a.h0a, a.h0b };
    f16* h1bufs[2] = { a.h1a, a.h1b };

    for (int t = 0; t < T_; ++t) {
        const f16* h0cur = h0bufs[t & 1];
        f16*       h0nxt = h0bufs[(t + 1) & 1];
        const f16* h1cur = h1bufs[t & 1];
        f16*       h1nxt = h1bufs[(t + 1) & 1];

        // layer 0: A = [h0 | emb_t], K=832, Cadd = ctxg (includes b0)
        gemm_cell<832, true, false>(
            h0cur, H_, a.embAll + (size_t)t * B_ * EW, EW, a.W0p,
            a.ctxg, nullptr, c0reg, h0nxt, nullptr, bm, bn, smem, tid);
        grid.sync();

        // layer 1: A = [h0_new | h1], K=1024, bias = b1p
        gemm_cell<1024, false, true>(
            h0nxt, H_, h1cur, H_, a.W1p,
            nullptr, a.b1p, c1reg, h1nxt, a.hs + (size_t)t * H_, bm, bn, smem, tid);
        grid.sync();
    }
}

// ---------------------------------------------------------------------------
// One-time packs / converts
// ---------------------------------------------------------------------------
__global__ __launch_bounds__(256)
void conv_f16_k(const float* __restrict__ src, f16* __restrict__ dst)
{
    const int i = blockIdx.x * 256 + threadIdx.x;
    const float4 v = reinterpret_cast<const float4*>(src)[i];
    f16x4 h = { (f16)v.x, (f16)v.y, (f16)v.z, (f16)v.w };
    *reinterpret_cast<f16x4*>(dst + (size_t)i * 4) = h;
}

__global__ __launch_bounds__(256)
void pack_wincell(const float* __restrict__ Win, const float* __restrict__ Wcell,
                  f16* __restrict__ dst)
{
    const int i = blockIdx.x * 256 + threadIdx.x;   // 1024*2560/4
    const int r = i / 640, c4 = (i % 640) * 4;
    const float* src = (r < 512) ? Win + (size_t)r * I_ + c4
                                 : Wcell + (size_t)(r - 512) * I_ + c4;
    const float4 v = *reinterpret_cast<const float4*>(src);
    f16x4 h = { (f16)v.x, (f16)v.y, (f16)v.z, (f16)v.w };
    *reinterpret_cast<f16x4*>(dst + (size_t)i * 4) = h;
}

// packed row rp -> (g, h): g = (rp>>4)&3, h = (rp>>6)*16 + (rp&15)
__global__ __launch_bounds__(256)
void pack_w0p(const float* __restrict__ Whh0, const float* __restrict__ Wih0,
              f16* __restrict__ W0)
{
    const int idx = blockIdx.x * 256 + threadIdx.x;   // 2048*832
    const int rp = idx / 832, k = idx % 832;
    const int g = (rp >> 4) & 3, h = (rp >> 6) * 16 + (rp & 15);
    const int srow = g * 512 + h;
    float v;
    if (k < 512)      v = Whh0[(size_t)srow * 512 + k];
    else if (k < 812) v = Wih0[(size_t)srow * 812 + (k - 512)];
    else              v = 0.0f;
    W0[idx] = (f16)v;
}

__global__ __launch_bounds__(256)
void pack_w1p(const float* __restrict__ Wih1, const float* __restrict__ Whh1,
              f16* __restrict__ W1)
{
    const int idx = blockIdx.x * 256 + threadIdx.x;   // 2048*1024
    const int rp = idx >> 10, k = idx & 1023;
    const int g = (rp >> 4) & 3, h = (rp >> 6) * 16 + (rp & 15);
    const int srow = g * 512 + h;
    const float v = (k < 512) ? Wih1[(size_t)srow * 512 + k]
                              : Whh1[(size_t)srow * 512 + (k - 512)];
    W1[idx] = (f16)v;
}

__global__ __launch_bounds__(256)
void pack_wctxp(const float* __restrict__ Wih0, f16* __restrict__ Wc)
{
    const int idx = blockIdx.x * 256 + threadIdx.x;   // 2048*512
    const int rp = idx >> 9, k = idx & 511;
    const int g = (rp >> 4) & 3, h = (rp >> 6) * 16 + (rp & 15);
    Wc[idx] = (f16)Wih0[(size_t)(g * 512 + h) * 812 + 300 + k];
}

__global__ __launch_bounds__(256)
void pack_b(const float* __restrict__ bih0, const float* __restrict__ bhh0,
            const float* __restrict__ bih1, const float* __restrict__ bhh1,
            float* __restrict__ b01p, float* __restrict__ b1p)
{
    const int idx = blockIdx.x * 256 + threadIdx.x;   // 4096
    const int c = idx & 2047;
    const int g = (c >> 4) & 3, h = (c >> 6) * 16 + (c & 15);
    const int s = g * 512 + h;
    if (idx < 2048) b01p[c] = bih0[s] + bhh0[s];
    else            b1p[c]  = bih1[s] + bhh1[s];
}

__global__ __launch_bounds__(256)
void pack_wout(const float* __restrict__ Wout, f16* __restrict__ Wo)
{
    const int i = blockIdx.x * 256 + threadIdx.x;     // 8064*512/4
    const int r = i >> 7, c4 = (i & 127) * 4;
    f16x4 h = { (f16)0.f, (f16)0.f, (f16)0.f, (f16)0.f };
    if (r < V_) {
        const float4 v = *reinterpret_cast<const float4*>(Wout + (size_t)r * H_ + c4);
        h = f16x4{ (f16)v.x, (f16)v.y, (f16)v.z, (f16)v.w };
    }
    *reinterpret_cast<f16x4*>(Wo + (size_t)i * 4) = h;
}

__global__ __launch_bounds__(256)
void pack_emb_all(const float* __restrict__ emb, const int* __restrict__ target,
                  f16* __restrict__ embAll)
{
    const int idx = blockIdx.x * 256 + threadIdx.x;   // 16*512*320
    const int t = idx / (B_ * EW);
    const int rem = idx % (B_ * EW);
    const int b = rem / EW, e = rem % EW;
    const int wd = (t == 0) ? SOS_ : target[b * T_ + (t - 1)];
    const float v = (e < E_) ? emb[(size_t)wd * E_ + e] : 0.0f;
    embAll[idx] = (f16)v;
}

__global__ __launch_bounds__(256)
void init_state(const float* __restrict__ ctxcc,
                const float* __restrict__ b_in,
                f16* __restrict__ ctx16, f16* __restrict__ h0, f16* __restrict__ h1)
{
    const int idx = blockIdx.x * 256 + threadIdx.x;   // 512*512
    const int b = idx >> 9, h = idx & 511;
    const f16 ch = (f16)(ctxcc[(size_t)b * 1024 + h] + b_in[h]);
    ctx16[idx] = ch;
    h0[idx] = ch;
    h1[idx] = ch;
}

// ---------------------------------------------------------------------------
extern "C" void kernel_launch(void* const* d_in, const int* in_sizes, int n_in,
                              void* d_out, int out_size, void* d_ws, size_t ws_size,
                              hipStream_t stream)
{
    const float* fused  = (const float*)d_in[0];
    const int*   target = (const int*)d_in[1];
    const float* emb    = (const float*)d_in[3];
    const float* W_in   = (const float*)d_in[4];
    const float* b_in   = (const float*)d_in[5];
    const float* W_cell = (const float*)d_in[6];
    const float* b_cell = (const float*)d_in[7];
    const float* W_ih0  = (const float*)d_in[8];
    const float* W_hh0  = (const float*)d_in[9];
    const float* b_ih0  = (const float*)d_in[10];
    const float* b_hh0  = (const float*)d_in[11];
    const float* W_ih1  = (const float*)d_in[12];
    const float* W_hh1  = (const float*)d_in[13];
    const float* b_ih1  = (const float*)d_in[14];
    const float* b_hh1  = (const float*)d_in[15];
    const float* W_out  = (const float*)d_in[16];
    const float* b_out  = (const float*)d_in[17];
    float* out = (float*)d_out;

    char* p = (char*)d_ws;
    auto carve = [&](size_t bytes) {
        char* r = p;
        p += (bytes + 255) & ~(size_t)255;
        return r;
    };
    float* ctxcc  = (float*)carve((size_t)B_ * 1024 * 4);
    float* ctxg   = (float*)carve((size_t)B_ * G4H * 4);
    float* b01p   = (float*)carve((size_t)G4H * 4);
    float* b1p    = (float*)carve((size_t)G4H * 4);
    f16* fused16  = (f16*)carve((size_t)B_ * I_ * 2);
    f16* WinCell  = (f16*)carve((size_t)1024 * I_ * 2);
    f16* W0p      = (f16*)carve((size_t)G4H * 832 * 2);
    f16* W1p      = (f16*)carve((size_t)G4H * 1024 * 2);
    f16* Wctxp    = (f16*)carve((size_t)G4H * H_ * 2);
    f16* Wout16   = (f16*)carve((size_t)VPAD * H_ * 2);
    f16* ctx16    = (f16*)carve((size_t)B_ * H_ * 2);
    f16* h0a      = (f16*)carve((size_t)B_ * H_ * 2);
    f16* h0b      = (f16*)carve((size_t)B_ * H_ * 2);
    f16* h1a      = (f16*)carve((size_t)B_ * H_ * 2);
    f16* h1b      = (f16*)carve((size_t)B_ * H_ * 2);
    f16* embAll   = (f16*)carve((size_t)T_ * B_ * EW * 2);
    f16* hs       = (f16*)carve((size_t)B_ * T_ * H_ * 2);

    // ---- one-time packs ----
    conv_f16_k  <<<(B_ * I_) / 1024, 256, 0, stream>>>(fused, fused16);
    pack_wincell<<<(1024 * I_) / 1024, 256, 0, stream>>>(W_in, W_cell, WinCell);
    pack_w0p    <<<(G4H * 832) / 256, 256, 0, stream>>>(W_hh0, W_ih0, W0p);
    pack_w1p    <<<(G4H * 1024) / 256, 256, 0, stream>>>(W_ih1, W_hh1, W1p);
    pack_wctxp  <<<(G4H * H_) / 256, 256, 0, stream>>>(W_ih0, Wctxp);
    pack_b      <<<(2 * G4H) / 256, 256, 0, stream>>>(b_ih0, b_hh0, b_ih1, b_hh1, b01p, b1p);
    pack_wout   <<<(VPAD * H_) / 1024, 256, 0, stream>>>(W_out, Wout16);
    pack_emb_all<<<(T_ * B_ * EW) / 256, 256, 0, stream>>>(emb, target, embAll);

    // ---- ctx / ccell in one GEMM: [512,1024] = fused16 @ [Win|Wcell]^T ----
    gemm_mfma<<<dim3(B_/128, 1024/128), 256, 0, stream>>>(
        fused16, I_, WinCell, I_, ctxcc, 1024, I_, 1024, nullptr, nullptr);

    init_state<<<(B_ * H_) / 256, 256, 0, stream>>>(ctxcc, b_in, ctx16, h0a, h1a);

    // ---- time-invariant ctx gate contribution (packed cols, + b0 biases) ----
    gemm_mfma<<<dim3(B_/128, G4H/128), 256, 0, stream>>>(
        ctx16, H_, Wctxp, H_, ctxg, G4H, H_, G4H, b01p, nullptr);

    // ---- persistent cooperative recurrent loop ----
    PArgs pa;
    pa.embAll = embAll; pa.W0p = W0p; pa.W1p = W1p;
    pa.ctxg = ctxg; pa.b1p = b1p; pa.ctxcc = ctxcc; pa.b_cell = b_cell;
    pa.h0a = h0a; pa.h0b = h0b; pa.h1a = h1a; pa.h1b = h1b; pa.hs = hs;
    void* kargs[] = { (void*)&pa };
    hipLaunchCooperativeKernel((const void*)lstm_persist,
                               dim3(256), dim3(256), kargs, 0, stream);

    // ---- output projection ----
    gemm_mfma<<<dim3((B_ * T_) / 128, VPAD / 128), 256, 0, stream>>>(
        hs, H_, Wout16, H_, out, V_, H_, V_, b_out, nullptr);
}

// Round 6
// 582.972 us; speedup vs baseline: 2.5527x; 2.5527x over previous
//
#include <hip/hip_runtime.h>
#include <cstdint>

#define B_   512
#define I_   2560
#define H_   512
#define E_   300
#define EW   320     // padded emb width
#define V_   8000
#define VPAD 8064    // 63 * 128
#define T_   16
#define G4H  2048
#define SOS_ 2

typedef _Float16 f16;
typedef _Float16 f16x8 __attribute__((ext_vector_type(8)));
typedef _Float16 f16x4 __attribute__((ext_vector_type(4)));
typedef float    f32x4 __attribute__((ext_vector_type(4)));

__device__ __forceinline__ float sigmoidf_(float x) {
    return 1.0f / (1.0f + __expf(-x));
}

__device__ __forceinline__ void gload16(const void* g, void* l) {
    __builtin_amdgcn_global_load_lds(
        (const __attribute__((address_space(1))) void*)g,
        (__attribute__((address_space(3))) void*)l,
        16, 0, 0);
}

// ---------------------------------------------------------------------------
// Generic MFMA f16 GEMM (m97 structure, verified rounds 2-4)
// ---------------------------------------------------------------------------
__global__ __launch_bounds__(256)
void gemm_mfma(const f16* __restrict__ A, int lda,
               const f16* __restrict__ Bw, int ldb,
               float* __restrict__ C, int ldc,
               int K, int Nvalid,
               const float* __restrict__ bias1,
               const float* __restrict__ bias2)
{
    __shared__ f16 As[128][32];
    __shared__ f16 Bs[128][32];

    const int tid  = threadIdx.x;
    const int w    = tid >> 6;
    const int lane = tid & 63;
    const int bm   = blockIdx.x * 128;
    const int bn   = blockIdx.y * 128;
    const int wr   = w >> 1;
    const int wc   = w & 1;

    const int srow = lane >> 2;
    const int skel = (lane & 3) * 8;

    const f16* Ag0 = A  + (size_t)(bm + w*32 +      srow) * lda + skel;
    const f16* Ag1 = A  + (size_t)(bm + w*32 + 16 + srow) * lda + skel;
    const f16* Bg0 = Bw + (size_t)(bn + w*32 +      srow) * ldb + skel;
    const f16* Bg1 = Bw + (size_t)(bn + w*32 + 16 + srow) * ldb + skel;
    f16* Al0 = &As[w*32     ][0];
    f16* Al1 = &As[w*32 + 16][0];
    f16* Bl0 = &Bs[w*32     ][0];
    f16* Bl1 = &Bs[w*32 + 16][0];

    const int frow = lane & 15;
    const int fk   = (lane >> 4) * 8;

    f32x4 acc[4][4] = {};

    for (int k0 = 0; k0 < K; k0 += 32) {
        gload16(Ag0 + k0, Al0);
        gload16(Ag1 + k0, Al1);
        gload16(Bg0 + k0, Bl0);
        gload16(Bg1 + k0, Bl1);
        __syncthreads();

        f16x8 af[4], bf[4];
        #pragma unroll
        for (int m = 0; m < 4; ++m)
            af[m] = *reinterpret_cast<const f16x8*>(&As[wr*64 + m*16 + frow][fk]);
        #pragma unroll
        for (int n = 0; n < 4; ++n)
            bf[n] = *reinterpret_cast<const f16x8*>(&Bs[wc*64 + n*16 + frow][fk]);

        #pragma unroll
        for (int m = 0; m < 4; ++m)
            #pragma unroll
            for (int n = 0; n < 4; ++n)
                acc[m][n] = __builtin_amdgcn_mfma_f32_16x16x32_f16(
                    af[m], bf[n], acc[m][n], 0, 0, 0);

        __syncthreads();
    }

    const int rowb = bm + wr*64 + (lane >> 4) * 4;
    #pragma unroll
    for (int n = 0; n < 4; ++n) {
        const int col = bn + wc*64 + n*16 + frow;
        if (col >= Nvalid) continue;
        float badd = 0.0f;
        if (bias1) badd += bias1[col];
        if (bias2) badd += bias2[col];
        #pragma unroll
        for (int m = 0; m < 4; ++m) {
            const int r0 = rowb + m*16;
            #pragma unroll
            for (int r = 0; r < 4; ++r)
                C[(size_t)(r0 + r) * ldc + col] = acc[m][n][r] + badd;
        }
    }
}

// ---------------------------------------------------------------------------
// Recurrent GEMM + fused LSTM cell body (verbatim round-3 gemm_step logic).
// C[64x128 tile] of [512, 2048(packed)] = [Ap1|Ap2] @ Wp^T.
// Packed cols: col = (h>>5)*128 + g*32 + (h&31), gate order i,f,g,o.
// BK=64 double-buffered staging, XOR-preswizzled global_load_lds source
// (linear LDS dest + swizzled read). Epilogue: gates -> LDS f32 [64][132]
// -> in-block cell update -> h out (f16).
// ---------------------------------------------------------------------------
__device__ __forceinline__ void gemm_cell_body(
    const f16* __restrict__ Ap1, const f16* __restrict__ Ap2, int lda2,
    const f16* __restrict__ Wp, int K,
    const float* __restrict__ Cadd,
    const float* __restrict__ bih, const float* __restrict__ bhh,
    float* __restrict__ cst,
    f16* __restrict__ hout1,
    f16* __restrict__ hout2, int h2stride,
    char* smem, int bm, int bn)
{
    const int tid  = threadIdx.x;
    const int w    = tid >> 6;
    const int lane = tid & 63;
    const int wr   = w >> 1, wc = w & 1;
    const int frow = lane & 15, hi = lane >> 4;
    const int sw   = (frow & 7) << 4;                       // read-side swizzle
    const int srow8 = lane >> 3;                            // staging row-in-line
    const int ksb  = ((((lane & 7) * 16) ^ (srow8 << 4)) >> 1);  // preswizzled k (f16)

    const int NT = K >> 6;
    f32x4 acc[2][4] = {};

    auto stage = [&](int bsel, int kt) {
        const int k0 = kt << 6;
        #pragma unroll
        for (int j = 0; j < 2; ++j) {                       // A: 2 lines/wave
            const int row = w*16 + j*8 + srow8;
            const f16* src;
            if (k0 < 512) src = Ap1 + (size_t)(bm + row) * 512  + k0 + ksb;
            else          src = Ap2 + (size_t)(bm + row) * lda2 + (k0 - 512) + ksb;
            gload16(src, smem + bsel*8192 + (w*2 + j)*1024 + lane*16);
        }
        #pragma unroll
        for (int j = 0; j < 4; ++j) {                       // B: 4 lines/wave
            const int row = w*32 + j*8 + srow8;
            gload16(Wp + (size_t)(bn + row) * K + k0 + ksb,
                    smem + 16384 + bsel*16384 + (w*4 + j)*1024 + lane*16);
        }
    };

    auto compute = [&](int bsel) {
        const char* As = smem + bsel*8192;
        const char* Bs = smem + 16384 + bsel*16384;
        #pragma unroll
        for (int ks = 0; ks < 2; ++ks) {
            const int cb = (ks*64 + hi*16) ^ sw;
            f16x8 af[2], bf[4];
            #pragma unroll
            for (int m = 0; m < 2; ++m)
                af[m] = *reinterpret_cast<const f16x8*>(As + (wr*32 + m*16 + frow)*128 + cb);
            #pragma unroll
            for (int n = 0; n < 4; ++n)
                bf[n] = *reinterpret_cast<const f16x8*>(Bs + (wc*64 + n*16 + frow)*128 + cb);
            #pragma unroll
            for (int m = 0; m < 2; ++m)
                #pragma unroll
                for (int n = 0; n < 4; ++n)
                    acc[m][n] = __builtin_amdgcn_mfma_f32_16x16x32_f16(
                        af[m], bf[n], acc[m][n], 0, 0, 0);
        }
    };

    stage(0, 0);
    __syncthreads();
    int buf = 0;
    for (int kt = 0; kt + 1 < NT; ++kt) {
        stage(buf ^ 1, kt + 1);     // prefetch next tile under compute
        compute(buf);
        __syncthreads();            // drains vmcnt -> next tile resident
        buf ^= 1;
    }
    compute(buf);
    __syncthreads();                // all LDS reads done; safe to alias as gates

    // gates -> LDS (+ Cadd), f32 [64][132]
    float* gs = (float*)smem;
    #pragma unroll
    for (int m = 0; m < 2; ++m) {
        const int row = wr*32 + m*16 + hi*4;
        #pragma unroll
        for (int n = 0; n < 4; ++n) {
            const int col = wc*64 + n*16 + frow;
            #pragma unroll
            for (int r = 0; r < 4; ++r) {
                float v = acc[m][n][r];
                if (Cadd) v += Cadd[(size_t)(bm + row + r) * G4H + bn + col];
                gs[(row + r)*132 + col] = v;
            }
        }
    }
    __syncthreads();

    // cell update: thread -> h' = tid&31, rows (tid>>5)*8 .. +8
    const int hp = tid & 31;
    const int hg = (bn >> 2) + hp;
    float bi0 = 0.f, bi1 = 0.f, bi2 = 0.f, bi3 = 0.f;
    if (bih) {
        bi0 = bih[hg]        + bhh[hg];
        bi1 = bih[512 + hg]  + bhh[512 + hg];
        bi2 = bih[1024 + hg] + bhh[1024 + hg];
        bi3 = bih[1536 + hg] + bhh[1536 + hg];
    }
    #pragma unroll
    for (int i = 0; i < 8; ++i) {
        const int r = (tid >> 5) * 8 + i;
        const int b = bm + r;
        const float gi = gs[r*132 +      hp] + bi0;
        const float gf = gs[r*132 + 32 + hp] + bi1;
        const float gc = gs[r*132 + 64 + hp] + bi2;
        const float go = gs[r*132 + 96 + hp] + bi3;
        const float c  = cst[(size_t)b * 512 + hg];
        const float cn = sigmoidf_(gf) * c + sigmoidf_(gi) * tanhf(gc);
        const float hn = sigmoidf_(go) * tanhf(cn);
        cst[(size_t)b * 512 + hg] = cn;
        hout1[(size_t)b * 512 + hg] = (f16)hn;
        if (hout2) hout2[(size_t)b * h2stride + hg] = (f16)hn;
    }
}

// ---------------------------------------------------------------------------
// Skewed step pair: one launch computes L0(p) on grid-z 0 and L1(p-1) on
// grid-z 1 — both depend only on the PREVIOUS launch's outputs, so stream
// order is the only synchronization needed (no grid sync, no coherence tax).
// ---------------------------------------------------------------------------
__global__ __launch_bounds__(256)
void step_pair(const f16* __restrict__ h0in,   // h0(p-1), also L1's A-half 1
               const f16* __restrict__ embt,   // emb(p)
               f16* __restrict__ h0out,        // h0(p)
               const f16* __restrict__ h1in,   // h1(p-2)
               f16* __restrict__ h1out,        // h1(p-1)
               f16* __restrict__ hsout,        // hs + (p-1)*H_
               const f16* __restrict__ W0p, const f16* __restrict__ W1p,
               const float* __restrict__ ctxg,
               const float* __restrict__ bih1, const float* __restrict__ bhh1,
               float* __restrict__ c0, float* __restrict__ c1,
               int active0, int active1)
{
    __shared__ char smem[49152];
    const int bm = blockIdx.x * 64;
    const int bn = blockIdx.y * 128;
    if (blockIdx.z == 0) {
        if (!active0) return;
        gemm_cell_body(h0in, embt, EW, W0p, 832,
                       ctxg, nullptr, nullptr,
                       c0, h0out, nullptr, 0, smem, bm, bn);
    } else {
        if (!active1) return;
        gemm_cell_body(h0in, h1in, 512, W1p, 1024,
                       nullptr, bih1, bhh1,
                       c1, h1out, hsout, T_ * H_, smem, bm, bn);
    }
}

// ---------------------------------------------------------------------------
// One-time packs / converts
// ---------------------------------------------------------------------------
__global__ __launch_bounds__(256)
void conv_f16_k(const float* __restrict__ src, f16* __restrict__ dst)
{
    const int i = blockIdx.x * 256 + threadIdx.x;
    const float4 v = reinterpret_cast<const float4*>(src)[i];
    f16x4 h = { (f16)v.x, (f16)v.y, (f16)v.z, (f16)v.w };
    *reinterpret_cast<f16x4*>(dst + (size_t)i * 4) = h;
}

__global__ __launch_bounds__(256)
void pack_wincell(const float* __restrict__ Win, const float* __restrict__ Wcell,
                  f16* __restrict__ dst)
{
    const int i = blockIdx.x * 256 + threadIdx.x;   // 1024*2560/4
    const int r = i / 640, c4 = (i % 640) * 4;
    const float* src = (r < 512) ? Win + (size_t)r * I_ + c4
                                 : Wcell + (size_t)(r - 512) * I_ + c4;
    const float4 v = *reinterpret_cast<const float4*>(src);
    f16x4 h = { (f16)v.x, (f16)v.y, (f16)v.z, (f16)v.w };
    *reinterpret_cast<f16x4*>(dst + (size_t)i * 4) = h;
}

// packed row rp -> (g, h): g = (rp>>5)&3, h = (rp>>7)*32 + (rp&31)
__global__ __launch_bounds__(256)
void pack_w0p(const float* __restrict__ Whh0, const float* __restrict__ Wih0,
              f16* __restrict__ W0)
{
    const int idx = blockIdx.x * 256 + threadIdx.x;   // 2048*832
    const int rp = idx / 832, k = idx % 832;
    const int g = (rp >> 5) & 3, h = (rp >> 7) * 32 + (rp & 31);
    const int srow = g * 512 + h;
    float v;
    if (k < 512)      v = Whh0[(size_t)srow * 512 + k];
    else if (k < 812) v = Wih0[(size_t)srow * 812 + (k - 512)];
    else              v = 0.0f;
    W0[idx] = (f16)v;
}

__global__ __launch_bounds__(256)
void pack_w1p(const float* __restrict__ Wih1, const float* __restrict__ Whh1,
              f16* __restrict__ W1)
{
    const int idx = blockIdx.x * 256 + threadIdx.x;   // 2048*1024
    const int rp = idx >> 10, k = idx & 1023;
    const int g = (rp >> 5) & 3, h = (rp >> 7) * 32 + (rp & 31);
    const int srow = g * 512 + h;
    const float v = (k < 512) ? Wih1[(size_t)srow * 512 + k]
                              : Whh1[(size_t)srow * 512 + (k - 512)];
    W1[idx] = (f16)v;
}

__global__ __launch_bounds__(256)
void pack_wctxp(const float* __restrict__ Wih0, f16* __restrict__ Wc)
{
    const int idx = blockIdx.x * 256 + threadIdx.x;   // 2048*512
    const int rp = idx >> 9, k = idx & 511;
    const int g = (rp >> 5) & 3, h = (rp >> 7) * 32 + (rp & 31);
    Wc[idx] = (f16)Wih0[(size_t)(g * 512 + h) * 812 + 300 + k];
}

__global__ __launch_bounds__(256)
void pack_b0(const float* __restrict__ bih0, const float* __restrict__ bhh0,
             float* __restrict__ b01p)
{
    const int idx = blockIdx.x * 256 + threadIdx.x;   // 2048
    const int g = (idx >> 5) & 3, h = (idx >> 7) * 32 + (idx & 31);
    b01p[idx] = bih0[g * 512 + h] + bhh0[g * 512 + h];
}

__global__ __launch_bounds__(256)
void pack_wout(const float* __restrict__ Wout, f16* __restrict__ Wo)
{
    const int i = blockIdx.x * 256 + threadIdx.x;     // 8064*512/4
    const int r = i >> 7, c4 = (i & 127) * 4;
    f16x4 h = { (f16)0.f, (f16)0.f, (f16)0.f, (f16)0.f };
    if (r < V_) {
        const float4 v = *reinterpret_cast<const float4*>(Wout + (size_t)r * H_ + c4);
        h = f16x4{ (f16)v.x, (f16)v.y, (f16)v.z, (f16)v.w };
    }
    *reinterpret_cast<f16x4*>(Wo + (size_t)i * 4) = h;
}

__global__ __launch_bounds__(256)
void pack_emb_all(const float* __restrict__ emb, const int* __restrict__ target,
                  f16* __restrict__ embAll)
{
    const int idx = blockIdx.x * 256 + threadIdx.x;   // 16*512*320
    const int t = idx / (B_ * EW);
    const int rem = idx % (B_ * EW);
    const int b = rem / EW, e = rem % EW;
    const int wd = (t == 0) ? SOS_ : target[b * T_ + (t - 1)];
    const float v = (e < E_) ? emb[(size_t)wd * E_ + e] : 0.0f;
    embAll[idx] = (f16)v;
}

__global__ __launch_bounds__(256)
void init_state(const float* __restrict__ ctxcc,
                const float* __restrict__ b_in, const float* __restrict__ b_cell,
                f16* __restrict__ ctx16, f16* __restrict__ h0, f16* __restrict__ h1,
                float* __restrict__ c0, float* __restrict__ c1)
{
    const int idx = blockIdx.x * 256 + threadIdx.x;   // 512*512
    const int b = idx >> 9, h = idx & 511;
    const float cv = ctxcc[(size_t)b * 1024 + h] + b_in[h];
    const float cc = ctxcc[(size_t)b * 1024 + 512 + h] + b_cell[h];
    const f16 ch = (f16)cv;
    ctx16[idx] = ch;
    h0[idx] = ch;
    h1[idx] = ch;
    c0[idx] = cc;
    c1[idx] = cc;
}

// ---------------------------------------------------------------------------
extern "C" void kernel_launch(void* const* d_in, const int* in_sizes, int n_in,
                              void* d_out, int out_size, void* d_ws, size_t ws_size,
                              hipStream_t stream)
{
    const float* fused  = (const float*)d_in[0];
    const int*   target = (const int*)d_in[1];
    const float* emb    = (const float*)d_in[3];
    const float* W_in   = (const float*)d_in[4];
    const float* b_in   = (const float*)d_in[5];
    const float* W_cell = (const float*)d_in[6];
    const float* b_cell = (const float*)d_in[7];
    const float* W_ih0  = (const float*)d_in[8];
    const float* W_hh0  = (const float*)d_in[9];
    const float* b_ih0  = (const float*)d_in[10];
    const float* b_hh0  = (const float*)d_in[11];
    const float* W_ih1  = (const float*)d_in[12];
    const float* W_hh1  = (const float*)d_in[13];
    const float* b_ih1  = (const float*)d_in[14];
    const float* b_hh1  = (const float*)d_in[15];
    const float* W_out  = (const float*)d_in[16];
    const float* b_out  = (const float*)d_in[17];
    float* out = (float*)d_out;

    char* p = (char*)d_ws;
    auto carve = [&](size_t bytes) {
        char* r = p;
        p += (bytes + 255) & ~(size_t)255;
        return r;
    };
    float* ctxcc  = (float*)carve((size_t)B_ * 1024 * 4);
    float* ctxg   = (float*)carve((size_t)B_ * G4H * 4);
    float* b01p   = (float*)carve((size_t)G4H * 4);
    float* c0     = (float*)carve((size_t)B_ * H_ * 4);
    float* c1     = (float*)carve((size_t)B_ * H_ * 4);
    f16* fused16  = (f16*)carve((size_t)B_ * I_ * 2);
    f16* WinCell  = (f16*)carve((size_t)1024 * I_ * 2);
    f16* W0p      = (f16*)carve((size_t)G4H * 832 * 2);
    f16* W1p      = (f16*)carve((size_t)G4H * 1024 * 2);
    f16* Wctxp    = (f16*)carve((size_t)G4H * H_ * 2);
    f16* Wout16   = (f16*)carve((size_t)VPAD * H_ * 2);
    f16* ctx16    = (f16*)carve((size_t)B_ * H_ * 2);
    f16* h0a      = (f16*)carve((size_t)B_ * H_ * 2);
    f16* h0b      = (f16*)carve((size_t)B_ * H_ * 2);
    f16* h1a      = (f16*)carve((size_t)B_ * H_ * 2);
    f16* h1b      = (f16*)carve((size_t)B_ * H_ * 2);
    f16* embAll   = (f16*)carve((size_t)T_ * B_ * EW * 2);
    f16* hs       = (f16*)carve((size_t)B_ * T_ * H_ * 2);

    // ---- one-time packs ----
    conv_f16_k  <<<(B_ * I_) / 1024, 256, 0, stream>>>(fused, fused16);
    pack_wincell<<<(1024 * I_) / 1024, 256, 0, stream>>>(W_in, W_cell, WinCell);
    pack_w0p    <<<(G4H * 832) / 256, 256, 0, stream>>>(W_hh0, W_ih0, W0p);
    pack_w1p    <<<(G4H * 1024) / 256, 256, 0, stream>>>(W_ih1, W_hh1, W1p);
    pack_wctxp  <<<(G4H * H_) / 256, 256, 0, stream>>>(W_ih0, Wctxp);
    pack_b0     <<<G4H / 256, 256, 0, stream>>>(b_ih0, b_hh0, b01p);
    pack_wout   <<<(VPAD * H_) / 1024, 256, 0, stream>>>(W_out, Wout16);
    pack_emb_all<<<(T_ * B_ * EW) / 256, 256, 0, stream>>>(emb, target, embAll);

    // ---- ctx / ccell in one GEMM: [512,1024] = fused16 @ [Win|Wcell]^T ----
    gemm_mfma<<<dim3(B_/128, 1024/128), 256, 0, stream>>>(
        fused16, I_, WinCell, I_, ctxcc, 1024, I_, 1024, nullptr, nullptr);

    // h0(-1), h1(-1) live in the parity-1 buffers (t & 1 convention, t = -1)
    init_state<<<(B_ * H_) / 256, 256, 0, stream>>>(
        ctxcc, b_in, b_cell, ctx16, h0b, h1b, c0, c1);

    // ---- time-invariant ctx gate contribution (packed cols, + b0 biases) ----
    gemm_mfma<<<dim3(B_/128, G4H/128), 256, 0, stream>>>(
        ctx16, H_, Wctxp, H_, ctxg, G4H, H_, G4H, b01p, nullptr);

    // ---- skewed recurrent loop: launch p computes L0(p) and L1(p-1) ----
    // h0(t) lives in h0buf[t&1]; h1(t) in h1buf[t&1].
    f16* h0buf[2] = { h0a, h0b };
    f16* h1buf[2] = { h1a, h1b };
    for (int phase = 0; phase <= T_; ++phase) {
        const int te = (phase < T_) ? phase : (T_ - 1);   // emb index (inactive at 16)
        const int t1 = (phase >= 1) ? (phase - 1) : 0;    // L1 timestep (inactive at 0)
        step_pair<<<dim3(B_/64, G4H/128, 2), 256, 0, stream>>>(
            h0buf[(phase + 1) & 1],                 // h0(phase-1)
            embAll + (size_t)te * B_ * EW,          // emb(phase)
            h0buf[phase & 1],                       // h0(phase) out
            h1buf[phase & 1],                       // h1(phase-2)
            h1buf[(phase + 1) & 1],                 // h1(phase-1) out
            hs + (size_t)t1 * H_,                   // hs row block for t1
            W0p, W1p, ctxg, b_ih1, b_hh1, c0, c1,
            (phase < T_) ? 1 : 0, (phase >= 1) ? 1 : 0);
    }

    // ---- output projection ----
    gemm_mfma<<<dim3((B_ * T_) / 128, VPAD / 128), 256, 0, stream>>>(
        hs, H_, Wout16, H_, out, V_, H_, V_, b_out, nullptr);
}

// Round 7
// 557.554 us; speedup vs baseline: 2.6691x; 1.0456x over previous
//
#include <hip/hip_runtime.h>
#include <cstdint>

#define B_   512
#define I_   2560
#define H_   512
#define E_   300
#define EW   320     // padded emb width
#define V_   8000
#define VPAD 8064    // 63 * 128
#define T_   16
#define G4H  2048
#define SOS_ 2

typedef _Float16 f16;
typedef _Float16 f16x8 __attribute__((ext_vector_type(8)));
typedef _Float16 f16x4 __attribute__((ext_vector_type(4)));
typedef float    f32x4 __attribute__((ext_vector_type(4)));

__device__ __forceinline__ float sigmoidf_(float x) {
    return 1.0f / (1.0f + __expf(-x));
}

__device__ __forceinline__ void gload16(const void* g, void* l) {
    __builtin_amdgcn_global_load_lds(
        (const __attribute__((address_space(1))) void*)g,
        (__attribute__((address_space(3))) void*)l,
        16, 0, 0);
}

// ---------------------------------------------------------------------------
// Generic MFMA f16 GEMM (m97 structure, verified rounds 2-6) — setup GEMMs.
// ---------------------------------------------------------------------------
__global__ __launch_bounds__(256)
void gemm_mfma(const f16* __restrict__ A, int lda,
               const f16* __restrict__ Bw, int ldb,
               float* __restrict__ C, int ldc,
               int K, int Nvalid,
               const float* __restrict__ bias1,
               const float* __restrict__ bias2)
{
    __shared__ f16 As[128][32];
    __shared__ f16 Bs[128][32];

    const int tid  = threadIdx.x;
    const int w    = tid >> 6;
    const int lane = tid & 63;
    const int bm   = blockIdx.x * 128;
    const int bn   = blockIdx.y * 128;
    const int wr   = w >> 1;
    const int wc   = w & 1;

    const int srow = lane >> 2;
    const int skel = (lane & 3) * 8;

    const f16* Ag0 = A  + (size_t)(bm + w*32 +      srow) * lda + skel;
    const f16* Ag1 = A  + (size_t)(bm + w*32 + 16 + srow) * lda + skel;
    const f16* Bg0 = Bw + (size_t)(bn + w*32 +      srow) * ldb + skel;
    const f16* Bg1 = Bw + (size_t)(bn + w*32 + 16 + srow) * ldb + skel;
    f16* Al0 = &As[w*32     ][0];
    f16* Al1 = &As[w*32 + 16][0];
    f16* Bl0 = &Bs[w*32     ][0];
    f16* Bl1 = &Bs[w*32 + 16][0];

    const int frow = lane & 15;
    const int fk   = (lane >> 4) * 8;

    f32x4 acc[4][4] = {};

    for (int k0 = 0; k0 < K; k0 += 32) {
        gload16(Ag0 + k0, Al0);
        gload16(Ag1 + k0, Al1);
        gload16(Bg0 + k0, Bl0);
        gload16(Bg1 + k0, Bl1);
        __syncthreads();

        f16x8 af[4], bf[4];
        #pragma unroll
        for (int m = 0; m < 4; ++m)
            af[m] = *reinterpret_cast<const f16x8*>(&As[wr*64 + m*16 + frow][fk]);
        #pragma unroll
        for (int n = 0; n < 4; ++n)
            bf[n] = *reinterpret_cast<const f16x8*>(&Bs[wc*64 + n*16 + frow][fk]);

        #pragma unroll
        for (int m = 0; m < 4; ++m)
            #pragma unroll
            for (int n = 0; n < 4; ++n)
                acc[m][n] = __builtin_amdgcn_mfma_f32_16x16x32_f16(
                    af[m], bf[n], acc[m][n], 0, 0, 0);

        __syncthreads();
    }

    const int rowb = bm + wr*64 + (lane >> 4) * 4;
    #pragma unroll
    for (int n = 0; n < 4; ++n) {
        const int col = bn + wc*64 + n*16 + frow;
        if (col >= Nvalid) continue;
        float badd = 0.0f;
        if (bias1) badd += bias1[col];
        if (bias2) badd += bias2[col];
        #pragma unroll
        for (int m = 0; m < 4; ++m) {
            const int r0 = rowb + m*16;
            #pragma unroll
            for (int r = 0; r < 4; ++r)
                C[(size_t)(r0 + r) * ldc + col] = acc[m][n][r] + badd;
        }
    }
}

// ---------------------------------------------------------------------------
// Recurrent GEMM + fused LSTM cell body (verified round 3/6).
// ---------------------------------------------------------------------------
__device__ __forceinline__ void gemm_cell_body(
    const f16* __restrict__ Ap1, const f16* __restrict__ Ap2, int lda2,
    const f16* __restrict__ Wp, int K,
    const float* __restrict__ Cadd,
    const float* __restrict__ bih, const float* __restrict__ bhh,
    float* __restrict__ cst,
    f16* __restrict__ hout1,
    char* smem, int bm, int bn)
{
    const int tid  = threadIdx.x;
    const int w    = tid >> 6;
    const int lane = tid & 63;
    const int wr   = w >> 1, wc = w & 1;
    const int frow = lane & 15, hi = lane >> 4;
    const int sw   = (frow & 7) << 4;                       // read-side swizzle
    const int srow8 = lane >> 3;
    const int ksb  = ((((lane & 7) * 16) ^ (srow8 << 4)) >> 1);  // preswizzled k

    const int NT = K >> 6;
    f32x4 acc[2][4] = {};

    auto stage = [&](int bsel, int kt) {
        const int k0 = kt << 6;
        #pragma unroll
        for (int j = 0; j < 2; ++j) {                       // A: 2 lines/wave
            const int row = w*16 + j*8 + srow8;
            const f16* src;
            if (k0 < 512) src = Ap1 + (size_t)(bm + row) * 512  + k0 + ksb;
            else          src = Ap2 + (size_t)(bm + row) * lda2 + (k0 - 512) + ksb;
            gload16(src, smem + bsel*8192 + (w*2 + j)*1024 + lane*16);
        }
        #pragma unroll
        for (int j = 0; j < 4; ++j) {                       // B: 4 lines/wave
            const int row = w*32 + j*8 + srow8;
            gload16(Wp + (size_t)(bn + row) * K + k0 + ksb,
                    smem + 16384 + bsel*16384 + (w*4 + j)*1024 + lane*16);
        }
    };

    auto compute = [&](int bsel) {
        const char* As = smem + bsel*8192;
        const char* Bs = smem + 16384 + bsel*16384;
        #pragma unroll
        for (int ks = 0; ks < 2; ++ks) {
            const int cb = (ks*64 + hi*16) ^ sw;
            f16x8 af[2], bf[4];
            #pragma unroll
            for (int m = 0; m < 2; ++m)
                af[m] = *reinterpret_cast<const f16x8*>(As + (wr*32 + m*16 + frow)*128 + cb);
            #pragma unroll
            for (int n = 0; n < 4; ++n)
                bf[n] = *reinterpret_cast<const f16x8*>(Bs + (wc*64 + n*16 + frow)*128 + cb);
            #pragma unroll
            for (int m = 0; m < 2; ++m)
                #pragma unroll
                for (int n = 0; n < 4; ++n)
                    acc[m][n] = __builtin_amdgcn_mfma_f32_16x16x32_f16(
                        af[m], bf[n], acc[m][n], 0, 0, 0);
        }
    };

    stage(0, 0);
    __syncthreads();
    int buf = 0;
    for (int kt = 0; kt + 1 < NT; ++kt) {
        stage(buf ^ 1, kt + 1);
        compute(buf);
        __syncthreads();
        buf ^= 1;
    }
    compute(buf);
    __syncthreads();

    // gates -> LDS (+ Cadd), f32 [64][132]
    float* gs = (float*)smem;
    #pragma unroll
    for (int m = 0; m < 2; ++m) {
        const int row = wr*32 + m*16 + hi*4;
        #pragma unroll
        for (int n = 0; n < 4; ++n) {
            const int col = wc*64 + n*16 + frow;
            #pragma unroll
            for (int r = 0; r < 4; ++r) {
                float v = acc[m][n][r];
                if (Cadd) v += Cadd[(size_t)(bm + row + r) * G4H + bn + col];
                gs[(row + r)*132 + col] = v;
            }
        }
    }
    __syncthreads();

    // cell update: thread -> h' = tid&31, rows (tid>>5)*8 .. +8
    const int hp = tid & 31;
    const int hg = (bn >> 2) + hp;
    float bi0 = 0.f, bi1 = 0.f, bi2 = 0.f, bi3 = 0.f;
    if (bih) {
        bi0 = bih[hg]        + bhh[hg];
        bi1 = bih[512 + hg]  + bhh[512 + hg];
        bi2 = bih[1024 + hg] + bhh[1024 + hg];
        bi3 = bih[1536 + hg] + bhh[1536 + hg];
    }
    #pragma unroll
    for (int i = 0; i < 8; ++i) {
        const int r = (tid >> 5) * 8 + i;
        const int b = bm + r;
        const float gi = gs[r*132 +      hp] + bi0;
        const float gf = gs[r*132 + 32 + hp] + bi1;
        const float gc = gs[r*132 + 64 + hp] + bi2;
        const float go = gs[r*132 + 96 + hp] + bi3;
        const float c  = cst[(size_t)b * 512 + hg];
        const float cn = sigmoidf_(gf) * c + sigmoidf_(gi) * tanhf(gc);
        const float hn = sigmoidf_(go) * tanhf(cn);
        cst[(size_t)b * 512 + hg] = cn;
        hout1[(size_t)b * 512 + hg] = (f16)hn;
    }
}

// ---------------------------------------------------------------------------
// Output-projection tile body: C128x128 of out(t) = h1(t) @ Wout^T + b_out.
// A = h1 [512][512] contiguous, Bw = Wout16 [8064][512], K = 512.
// C row r -> out[(r*16 + t)*8000 + col]  (handled via base offset + ldc).
// ---------------------------------------------------------------------------
__device__ __forceinline__ void gemm_out_body(
    const f16* __restrict__ A, const f16* __restrict__ Bw,
    float* __restrict__ C,     // = out + t*V_
    const float* __restrict__ bias,
    int bm, int bn, char* smem, int tid)
{
    f16 (*As)[32] = (f16(*)[32])smem;
    f16 (*Bs)[32] = (f16(*)[32])(smem + 8192);

    const int w    = tid >> 6;
    const int lane = tid & 63;
    const int wr   = w >> 1, wc = w & 1;
    const int srow = lane >> 2;
    const int skel = (lane & 3) * 8;

    const f16* Ag0 = A  + (size_t)(bm + w*32 +      srow) * 512 + skel;
    const f16* Ag1 = A  + (size_t)(bm + w*32 + 16 + srow) * 512 + skel;
    const f16* Bg0 = Bw + (size_t)(bn + w*32 +      srow) * 512 + skel;
    const f16* Bg1 = Bw + (size_t)(bn + w*32 + 16 + srow) * 512 + skel;
    f16* Al0 = &As[w*32     ][0];
    f16* Al1 = &As[w*32 + 16][0];
    f16* Bl0 = &Bs[w*32     ][0];
    f16* Bl1 = &Bs[w*32 + 16][0];

    const int frow = lane & 15;
    const int fk   = (lane >> 4) * 8;

    f32x4 acc[4][4] = {};

    for (int k0 = 0; k0 < 512; k0 += 32) {
        gload16(Ag0 + k0, Al0);
        gload16(Ag1 + k0, Al1);
        gload16(Bg0 + k0, Bl0);
        gload16(Bg1 + k0, Bl1);
        __syncthreads();

        f16x8 af[4], bf[4];
        #pragma unroll
        for (int m = 0; m < 4; ++m)
            af[m] = *reinterpret_cast<const f16x8*>(&As[wr*64 + m*16 + frow][fk]);
        #pragma unroll
        for (int n = 0; n < 4; ++n)
            bf[n] = *reinterpret_cast<const f16x8*>(&Bs[wc*64 + n*16 + frow][fk]);

        #pragma unroll
        for (int m = 0; m < 4; ++m)
            #pragma unroll
            for (int n = 0; n < 4; ++n)
                acc[m][n] = __builtin_amdgcn_mfma_f32_16x16x32_f16(
                    af[m], bf[n], acc[m][n], 0, 0, 0);

        __syncthreads();
    }

    const int rowb = bm + wr*64 + (lane >> 4) * 4;
    #pragma unroll
    for (int n = 0; n < 4; ++n) {
        const int col = bn + wc*64 + n*16 + frow;
        if (col >= V_) continue;
        const float badd = bias[col];
        #pragma unroll
        for (int m = 0; m < 4; ++m) {
            const int r0 = rowb + m*16;
            #pragma unroll
            for (int r = 0; r < 4; ++r)
                C[(size_t)(r0 + r) * (T_ * V_) + col] = acc[m][n][r] + badd;
        }
    }
}

// ---------------------------------------------------------------------------
// Fused phase kernel: flat 508-block grid.
//   [0,128)   L0(p):   h0out = cell(h0in | emb_p)      (active0)
//   [128,256) L1(p-1): h1out = cell(h0in | h1in)       (active1)
//   [256,508) OUT(p-2): out_t = h1in @ Wout^T + b_out  (activeO, t = tout)
// All dependencies are on the PREVIOUS launch's buffers — stream order only.
// ---------------------------------------------------------------------------
__global__ __launch_bounds__(256)
void phase_kernel(const f16* __restrict__ h0in,   // h0(p-1)
                  const f16* __restrict__ embt,   // emb(p)
                  f16* __restrict__ h0out,        // h0(p)
                  const f16* __restrict__ h1in,   // h1(p-2): L1 input + OUT src
                  f16* __restrict__ h1out,        // h1(p-1)
                  const f16* __restrict__ W0p, const f16* __restrict__ W1p,
                  const f16* __restrict__ WoutP,
                  const float* __restrict__ ctxg,
                  const float* __restrict__ bih1, const float* __restrict__ bhh1,
                  const float* __restrict__ b_out,
                  float* __restrict__ c0, float* __restrict__ c1,
                  float* __restrict__ out, int tout,
                  int active0, int active1, int activeO)
{
    __shared__ char smem[49152];
    const int bx = blockIdx.x;

    if (bx < 128) {
        if (!active0) return;
        const int bm = (bx & 7) * 64, bn = (bx >> 3) * 128;
        gemm_cell_body(h0in, embt, EW, W0p, 832,
                       ctxg, nullptr, nullptr, c0, h0out, smem, bm, bn);
    } else if (bx < 256) {
        if (!active1) return;
        const int lb = bx - 128;
        const int bm = (lb & 7) * 64, bn = (lb >> 3) * 128;
        gemm_cell_body(h0in, h1in, 512, W1p, 1024,
                       nullptr, bih1, bhh1, c1, h1out, smem, bm, bn);
    } else {
        if (!activeO) return;
        const int o = bx - 256;                     // 0..251
        const int bm = (o & 3) * 128, bn = (o >> 2) * 128;
        gemm_out_body(h1in, WoutP, out + (size_t)tout * V_, b_out,
                      bm, bn, smem, threadIdx.x);
    }
}

// ---------------------------------------------------------------------------
// One-time packs / converts
// ---------------------------------------------------------------------------
__global__ __launch_bounds__(256)
void conv_f16_k(const float* __restrict__ src, f16* __restrict__ dst)
{
    const int i = blockIdx.x * 256 + threadIdx.x;
    const float4 v = reinterpret_cast<const float4*>(src)[i];
    f16x4 h = { (f16)v.x, (f16)v.y, (f16)v.z, (f16)v.w };
    *reinterpret_cast<f16x4*>(dst + (size_t)i * 4) = h;
}

__global__ __launch_bounds__(256)
void pack_wincell(const float* __restrict__ Win, const float* __restrict__ Wcell,
                  f16* __restrict__ dst)
{
    const int i = blockIdx.x * 256 + threadIdx.x;   // 1024*2560/4
    const int r = i / 640, c4 = (i % 640) * 4;
    const float* src = (r < 512) ? Win + (size_t)r * I_ + c4
                                 : Wcell + (size_t)(r - 512) * I_ + c4;
    const float4 v = *reinterpret_cast<const float4*>(src);
    f16x4 h = { (f16)v.x, (f16)v.y, (f16)v.z, (f16)v.w };
    *reinterpret_cast<f16x4*>(dst + (size_t)i * 4) = h;
}

// packed row rp -> (g, h): g = (rp>>5)&3, h = (rp>>7)*32 + (rp&31)
__global__ __launch_bounds__(256)
void pack_w0p(const float* __restrict__ Whh0, const float* __restrict__ Wih0,
              f16* __restrict__ W0)
{
    const int idx = blockIdx.x * 256 + threadIdx.x;   // 2048*832
    const int rp = idx / 832, k = idx % 832;
    const int g = (rp >> 5) & 3, h = (rp >> 7) * 32 + (rp & 31);
    const int srow = g * 512 + h;
    float v;
    if (k < 512)      v = Whh0[(size_t)srow * 512 + k];
    else if (k < 812) v = Wih0[(size_t)srow * 812 + (k - 512)];
    else              v = 0.0f;
    W0[idx] = (f16)v;
}

__global__ __launch_bounds__(256)
void pack_w1p(const float* __restrict__ Wih1, const float* __restrict__ Whh1,
              f16* __restrict__ W1)
{
    const int idx = blockIdx.x * 256 + threadIdx.x;   // 2048*1024
    const int rp = idx >> 10, k = idx & 1023;
    const int g = (rp >> 5) & 3, h = (rp >> 7) * 32 + (rp & 31);
    const int srow = g * 512 + h;
    const float v = (k < 512) ? Wih1[(size_t)srow * 512 + k]
                              : Whh1[(size_t)srow * 512 + (k - 512)];
    W1[idx] = (f16)v;
}

__global__ __launch_bounds__(256)
void pack_wctxp(const float* __restrict__ Wih0, f16* __restrict__ Wc)
{
    const int idx = blockIdx.x * 256 + threadIdx.x;   // 2048*512
    const int rp = idx >> 9, k = idx & 511;
    const int g = (rp >> 5) & 3, h = (rp >> 7) * 32 + (rp & 31);
    Wc[idx] = (f16)Wih0[(size_t)(g * 512 + h) * 812 + 300 + k];
}

__global__ __launch_bounds__(256)
void pack_b0(const float* __restrict__ bih0, const float* __restrict__ bhh0,
             float* __restrict__ b01p)
{
    const int idx = blockIdx.x * 256 + threadIdx.x;   // 2048
    const int g = (idx >> 5) & 3, h = (idx >> 7) * 32 + (idx & 31);
    b01p[idx] = bih0[g * 512 + h] + bhh0[g * 512 + h];
}

__global__ __launch_bounds__(256)
void pack_wout(const float* __restrict__ Wout, f16* __restrict__ Wo)
{
    const int i = blockIdx.x * 256 + threadIdx.x;     // 8064*512/4
    const int r = i >> 7, c4 = (i & 127) * 4;
    f16x4 h = { (f16)0.f, (f16)0.f, (f16)0.f, (f16)0.f };
    if (r < V_) {
        const float4 v = *reinterpret_cast<const float4*>(Wout + (size_t)r * H_ + c4);
        h = f16x4{ (f16)v.x, (f16)v.y, (f16)v.z, (f16)v.w };
    }
    *reinterpret_cast<f16x4*>(Wo + (size_t)i * 4) = h;
}

__global__ __launch_bounds__(256)
void pack_emb_all(const float* __restrict__ emb, const int* __restrict__ target,
                  f16* __restrict__ embAll)
{
    const int idx = blockIdx.x * 256 + threadIdx.x;   // 16*512*320
    const int t = idx / (B_ * EW);
    const int rem = idx % (B_ * EW);
    const int b = rem / EW, e = rem % EW;
    const int wd = (t == 0) ? SOS_ : target[b * T_ + (t - 1)];
    const float v = (e < E_) ? emb[(size_t)wd * E_ + e] : 0.0f;
    embAll[idx] = (f16)v;
}

__global__ __launch_bounds__(256)
void init_state(const float* __restrict__ ctxcc,
                const float* __restrict__ b_in, const float* __restrict__ b_cell,
                f16* __restrict__ ctx16, f16* __restrict__ h0, f16* __restrict__ h1,
                float* __restrict__ c0, float* __restrict__ c1)
{
    const int idx = blockIdx.x * 256 + threadIdx.x;   // 512*512
    const int b = idx >> 9, h = idx & 511;
    const float cv = ctxcc[(size_t)b * 1024 + h] + b_in[h];
    const float cc = ctxcc[(size_t)b * 1024 + 512 + h] + b_cell[h];
    const f16 ch = (f16)cv;
    ctx16[idx] = ch;
    h0[idx] = ch;
    h1[idx] = ch;
    c0[idx] = cc;
    c1[idx] = cc;
}

// ---------------------------------------------------------------------------
extern "C" void kernel_launch(void* const* d_in, const int* in_sizes, int n_in,
                              void* d_out, int out_size, void* d_ws, size_t ws_size,
                              hipStream_t stream)
{
    const float* fused  = (const float*)d_in[0];
    const int*   target = (const int*)d_in[1];
    const float* emb    = (const float*)d_in[3];
    const float* W_in   = (const float*)d_in[4];
    const float* b_in   = (const float*)d_in[5];
    const float* W_cell = (const float*)d_in[6];
    const float* b_cell = (const float*)d_in[7];
    const float* W_ih0  = (const float*)d_in[8];
    const float* W_hh0  = (const float*)d_in[9];
    const float* b_ih0  = (const float*)d_in[10];
    const float* b_hh0  = (const float*)d_in[11];
    const float* W_ih1  = (const float*)d_in[12];
    const float* W_hh1  = (const float*)d_in[13];
    const float* b_ih1  = (const float*)d_in[14];
    const float* b_hh1  = (const float*)d_in[15];
    const float* W_out  = (const float*)d_in[16];
    const float* b_out  = (const float*)d_in[17];
    float* out = (float*)d_out;

    char* p = (char*)d_ws;
    auto carve = [&](size_t bytes) {
        char* r = p;
        p += (bytes + 255) & ~(size_t)255;
        return r;
    };
    float* ctxcc  = (float*)carve((size_t)B_ * 1024 * 4);
    float* ctxg   = (float*)carve((size_t)B_ * G4H * 4);
    float* b01p   = (float*)carve((size_t)G4H * 4);
    float* c0     = (float*)carve((size_t)B_ * H_ * 4);
    float* c1     = (float*)carve((size_t)B_ * H_ * 4);
    f16* fused16  = (f16*)carve((size_t)B_ * I_ * 2);
    f16* WinCell  = (f16*)carve((size_t)1024 * I_ * 2);
    f16* W0p      = (f16*)carve((size_t)G4H * 832 * 2);
    f16* W1p      = (f16*)carve((size_t)G4H * 1024 * 2);
    f16* Wctxp    = (f16*)carve((size_t)G4H * H_ * 2);
    f16* Wout16   = (f16*)carve((size_t)VPAD * H_ * 2);
    f16* ctx16    = (f16*)carve((size_t)B_ * H_ * 2);
    f16* h0a      = (f16*)carve((size_t)B_ * H_ * 2);
    f16* h0b      = (f16*)carve((size_t)B_ * H_ * 2);
    f16* h1a      = (f16*)carve((size_t)B_ * H_ * 2);
    f16* h1b      = (f16*)carve((size_t)B_ * H_ * 2);
    f16* embAll   = (f16*)carve((size_t)T_ * B_ * EW * 2);

    // ---- one-time packs ----
    conv_f16_k  <<<(B_ * I_) / 1024, 256, 0, stream>>>(fused, fused16);
    pack_wincell<<<(1024 * I_) / 1024, 256, 0, stream>>>(W_in, W_cell, WinCell);
    pack_w0p    <<<(G4H * 832) / 256, 256, 0, stream>>>(W_hh0, W_ih0, W0p);
    pack_w1p    <<<(G4H * 1024) / 256, 256, 0, stream>>>(W_ih1, W_hh1, W1p);
    pack_wctxp  <<<(G4H * H_) / 256, 256, 0, stream>>>(W_ih0, Wctxp);
    pack_b0     <<<G4H / 256, 256, 0, stream>>>(b_ih0, b_hh0, b01p);
    pack_wout   <<<(VPAD * H_) / 1024, 256, 0, stream>>>(W_out, Wout16);
    pack_emb_all<<<(T_ * B_ * EW) / 256, 256, 0, stream>>>(emb, target, embAll);

    // ---- ctx / ccell in one GEMM: [512,1024] = fused16 @ [Win|Wcell]^T ----
    gemm_mfma<<<dim3(B_/128, 1024/128), 256, 0, stream>>>(
        fused16, I_, WinCell, I_, ctxcc, 1024, I_, 1024, nullptr, nullptr);

    // h0(-1), h1(-1) live in the parity-1 buffers
    init_state<<<(B_ * H_) / 256, 256, 0, stream>>>(
        ctxcc, b_in, b_cell, ctx16, h0b, h1b, c0, c1);

    // ---- time-invariant ctx gate contribution (packed cols, + b0 biases) ----
    gemm_mfma<<<dim3(B_/128, G4H/128), 256, 0, stream>>>(
        ctx16, H_, Wctxp, H_, ctxg, G4H, H_, G4H, b01p, nullptr);

    // ---- skewed recurrent + fused out-projection: phases 0..17 ----
    // h0(t) in h0buf[t&1]; h1(t) in h1buf[t&1].
    // Phase p: L0 -> h0(p); L1 -> h1(p-1); OUT -> logits(t = p-2).
    f16* h0buf[2] = { h0a, h0b };
    f16* h1buf[2] = { h1a, h1b };
    for (int phase = 0; phase <= T_ + 1; ++phase) {
        const int a0 = (phase < T_) ? 1 : 0;
        const int a1 = (phase >= 1 && phase <= T_) ? 1 : 0;
        const int aO = (phase >= 2) ? 1 : 0;
        const int te = (phase < T_) ? phase : (T_ - 1);
        const int tO = aO ? (phase - 2) : 0;
        phase_kernel<<<dim3(508), 256, 0, stream>>>(
            h0buf[(phase + 1) & 1],                 // h0(p-1)
            embAll + (size_t)te * B_ * EW,          // emb(p)
            h0buf[phase & 1],                       // h0(p) out
            h1buf[phase & 1],                       // h1(p-2): L1 input + OUT src
            h1buf[(phase + 1) & 1],                 // h1(p-1) out
            W0p, W1p, Wout16, ctxg, b_ih1, b_hh1, b_out,
            c0, c1, out, tO, a0, a1, aO);
    }
}

// Round 8
// 483.772 us; speedup vs baseline: 3.0761x; 1.1525x over previous
//
#include <hip/hip_runtime.h>
#include <cstdint>

#define B_   512
#define I_   2560
#define H_   512
#define E_   300
#define EW   320     // padded emb width
#define V_   8000
#define VPAD 8064    // 63 * 128
#define T_   16
#define G4H  2048
#define SOS_ 2

typedef _Float16 f16;
typedef _Float16 f16x8 __attribute__((ext_vector_type(8)));
typedef _Float16 f16x4 __attribute__((ext_vector_type(4)));
typedef float    f32x4 __attribute__((ext_vector_type(4)));

__device__ __forceinline__ float sigmoidf_(float x) {
    return 1.0f / (1.0f + __expf(-x));
}

__device__ __forceinline__ void gload16(const void* g, void* l) {
    __builtin_amdgcn_global_load_lds(
        (const __attribute__((address_space(1))) void*)g,
        (__attribute__((address_space(3))) void*)l,
        16, 0, 0);
}

// ---------------------------------------------------------------------------
// Generic MFMA f16 GEMM (m97 structure, verified rounds 2-7) — setup GEMMs.
// ---------------------------------------------------------------------------
__global__ __launch_bounds__(256)
void gemm_mfma(const f16* __restrict__ A, int lda,
               const f16* __restrict__ Bw, int ldb,
               float* __restrict__ C, int ldc,
               int K, int Nvalid,
               const float* __restrict__ bias1,
               const float* __restrict__ bias2)
{
    __shared__ f16 As[128][32];
    __shared__ f16 Bs[128][32];

    const int tid  = threadIdx.x;
    const int w    = tid >> 6;
    const int lane = tid & 63;
    const int bm   = blockIdx.x * 128;
    const int bn   = blockIdx.y * 128;
    const int wr   = w >> 1;
    const int wc   = w & 1;

    const int srow = lane >> 2;
    const int skel = (lane & 3) * 8;

    const f16* Ag0 = A  + (size_t)(bm + w*32 +      srow) * lda + skel;
    const f16* Ag1 = A  + (size_t)(bm + w*32 + 16 + srow) * lda + skel;
    const f16* Bg0 = Bw + (size_t)(bn + w*32 +      srow) * ldb + skel;
    const f16* Bg1 = Bw + (size_t)(bn + w*32 + 16 + srow) * ldb + skel;
    f16* Al0 = &As[w*32     ][0];
    f16* Al1 = &As[w*32 + 16][0];
    f16* Bl0 = &Bs[w*32     ][0];
    f16* Bl1 = &Bs[w*32 + 16][0];

    const int frow = lane & 15;
    const int fk   = (lane >> 4) * 8;

    f32x4 acc[4][4] = {};

    for (int k0 = 0; k0 < K; k0 += 32) {
        gload16(Ag0 + k0, Al0);
        gload16(Ag1 + k0, Al1);
        gload16(Bg0 + k0, Bl0);
        gload16(Bg1 + k0, Bl1);
        __syncthreads();

        f16x8 af[4], bf[4];
        #pragma unroll
        for (int m = 0; m < 4; ++m)
            af[m] = *reinterpret_cast<const f16x8*>(&As[wr*64 + m*16 + frow][fk]);
        #pragma unroll
        for (int n = 0; n < 4; ++n)
            bf[n] = *reinterpret_cast<const f16x8*>(&Bs[wc*64 + n*16 + frow][fk]);

        #pragma unroll
        for (int m = 0; m < 4; ++m)
            #pragma unroll
            for (int n = 0; n < 4; ++n)
                acc[m][n] = __builtin_amdgcn_mfma_f32_16x16x32_f16(
                    af[m], bf[n], acc[m][n], 0, 0, 0);

        __syncthreads();
    }

    const int rowb = bm + wr*64 + (lane >> 4) * 4;
    #pragma unroll
    for (int n = 0; n < 4; ++n) {
        const int col = bn + wc*64 + n*16 + frow;
        if (col >= Nvalid) continue;
        float badd = 0.0f;
        if (bias1) badd += bias1[col];
        if (bias2) badd += bias2[col];
        #pragma unroll
        for (int m = 0; m < 4; ++m) {
            const int r0 = rowb + m*16;
            #pragma unroll
            for (int r = 0; r < 4; ++r)
                C[(size_t)(r0 + r) * ldc + col] = acc[m][n][r] + badd;
        }
    }
}

// ---------------------------------------------------------------------------
// Recurrent GEMM + fused LSTM cell body, depth-2 counted-vmcnt pipeline.
// Per K-tile (BK=64): wait own tile loads (vmcnt(6): 1 tile in flight) ->
// s_barrier -> ds_read all fragments to regs -> lgkmcnt(0) -> s_barrier ->
// stage tile kt+2 into the just-freed buffer -> MFMA.  No vmcnt(0) drains.
// LDS: A bufs 2x8KB @0, W bufs 2x16KB @16K (48KB); epilogue gs aliases @0.
// ---------------------------------------------------------------------------
__device__ __forceinline__ void gemm_cell_body(
    const f16* __restrict__ Ap1, const f16* __restrict__ Ap2, int lda2,
    const f16* __restrict__ Wp, int K,
    const float* __restrict__ Cadd,
    const float* __restrict__ bih, const float* __restrict__ bhh,
    float* __restrict__ cst,
    f16* __restrict__ hout1,
    char* smem, int bm, int bn)
{
    const int tid  = threadIdx.x;
    const int w    = tid >> 6;
    const int lane = tid & 63;
    const int wr   = w >> 1, wc = w & 1;
    const int frow = lane & 15, hi = lane >> 4;
    const int sw   = (frow & 7) << 4;                       // read-side swizzle
    const int srow8 = lane >> 3;
    const int ksb  = ((((lane & 7) * 16) ^ (srow8 << 4)) >> 1);  // preswizzled k

    const int NT = K >> 6;
    f32x4 acc[2][4] = {};

    char* Abuf = smem;            // 2 x 8192
    char* Wbuf = smem + 16384;    // 2 x 16384

    auto stage = [&](int bsel, int kt) {
        const int k0 = kt << 6;
        #pragma unroll
        for (int j = 0; j < 2; ++j) {                       // A: 2 lines/wave
            const int row = w*16 + j*8 + srow8;
            const f16* src;
            if (k0 < 512) src = Ap1 + (size_t)(bm + row) * 512  + k0 + ksb;
            else          src = Ap2 + (size_t)(bm + row) * lda2 + (k0 - 512) + ksb;
            gload16(src, Abuf + bsel*8192 + (w*2 + j)*1024 + lane*16);
        }
        #pragma unroll
        for (int j = 0; j < 4; ++j) {                       // B: 4 lines/wave
            const int row = w*32 + j*8 + srow8;
            gload16(Wp + (size_t)(bn + row) * K + k0 + ksb,
                    Wbuf + bsel*16384 + (w*4 + j)*1024 + lane*16);
        }
    };

    stage(0, 0);
    stage(1, 1);

    int buf = 0;
    for (int kt = 0; kt < NT; ++kt) {
        // wait for this tile's 6 loads (1 tile = 6 loads may stay in flight)
        if (kt < NT - 1) asm volatile("s_waitcnt vmcnt(6)" ::: "memory");
        else             asm volatile("s_waitcnt vmcnt(0)" ::: "memory");
        __builtin_amdgcn_sched_barrier(0);
        __builtin_amdgcn_s_barrier();            // tile kt visible to all
        __builtin_amdgcn_sched_barrier(0);

        const char* A_ = Abuf + buf*8192;
        const char* W_ = Wbuf + buf*16384;
        f16x8 af[2][2], bf[2][4];
        #pragma unroll
        for (int ks = 0; ks < 2; ++ks) {
            const int cb = (ks*64 + hi*16) ^ sw;
            #pragma unroll
            for (int m = 0; m < 2; ++m)
                af[ks][m] = *reinterpret_cast<const f16x8*>(A_ + (wr*32 + m*16 + frow)*128 + cb);
            #pragma unroll
            for (int n = 0; n < 4; ++n)
                bf[ks][n] = *reinterpret_cast<const f16x8*>(W_ + (wc*64 + n*16 + frow)*128 + cb);
        }
        __builtin_amdgcn_sched_barrier(0);
        asm volatile("s_waitcnt lgkmcnt(0)" ::: "memory");   // my reads in regs
        __builtin_amdgcn_sched_barrier(0);
        __builtin_amdgcn_s_barrier();            // ALL reads of tile kt done
        __builtin_amdgcn_sched_barrier(0);

        if (kt + 2 < NT) stage(buf, kt + 2);     // overwrite freed buffer

        #pragma unroll
        for (int ks = 0; ks < 2; ++ks)
            #pragma unroll
            for (int m = 0; m < 2; ++m)
                #pragma unroll
                for (int n = 0; n < 4; ++n)
                    acc[m][n] = __builtin_amdgcn_mfma_f32_16x16x32_f16(
                        af[ks][m], bf[ks][n], acc[m][n], 0, 0, 0);
        buf ^= 1;
    }

    // gates -> LDS (+ Cadd), f32 [64][132]; LDS free after last barrier
    float* gs = (float*)smem;
    #pragma unroll
    for (int m = 0; m < 2; ++m) {
        const int row = wr*32 + m*16 + hi*4;
        #pragma unroll
        for (int n = 0; n < 4; ++n) {
            const int col = wc*64 + n*16 + frow;
            #pragma unroll
            for (int r = 0; r < 4; ++r) {
                float v = acc[m][n][r];
                if (Cadd) v += Cadd[(size_t)(bm + row + r) * G4H + bn + col];
                gs[(row + r)*132 + col] = v;
            }
        }
    }
    __syncthreads();

    // cell update: thread -> h' = tid&31, rows (tid>>5)*8 .. +8
    const int hp = tid & 31;
    const int hg = (bn >> 2) + hp;
    float bi0 = 0.f, bi1 = 0.f, bi2 = 0.f, bi3 = 0.f;
    if (bih) {
        bi0 = bih[hg]        + bhh[hg];
        bi1 = bih[512 + hg]  + bhh[512 + hg];
        bi2 = bih[1024 + hg] + bhh[1024 + hg];
        bi3 = bih[1536 + hg] + bhh[1536 + hg];
    }
    #pragma unroll
    for (int i = 0; i < 8; ++i) {
        const int r = (tid >> 5) * 8 + i;
        const int b = bm + r;
        const float gi = gs[r*132 +      hp] + bi0;
        const float gf = gs[r*132 + 32 + hp] + bi1;
        const float gc = gs[r*132 + 64 + hp] + bi2;
        const float go = gs[r*132 + 96 + hp] + bi3;
        const float c  = cst[(size_t)b * 512 + hg];
        const float cn = sigmoidf_(gf) * c + sigmoidf_(gi) * tanhf(gc);
        const float hn = sigmoidf_(go) * tanhf(cn);
        cst[(size_t)b * 512 + hg] = cn;
        hout1[(size_t)b * 512 + hg] = (f16)hn;
    }
}

// ---------------------------------------------------------------------------
// Output-projection tile body (m97 layout), depth-3 counted-vmcnt pipeline.
// K=512, BK=32, NT=16, 4 loads/tile. LDS: As 3x8KB @0, Bs 3x8KB @24K (48KB).
// ---------------------------------------------------------------------------
__device__ __forceinline__ void gemm_out_body(
    const f16* __restrict__ A, const f16* __restrict__ Bw,
    float* __restrict__ C,     // = out + t*V_
    const float* __restrict__ bias,
    int bm, int bn, char* smem, int tid)
{
    const int w    = tid >> 6;
    const int lane = tid & 63;
    const int wr   = w >> 1, wc = w & 1;
    const int srow = lane >> 2;
    const int skel = (lane & 3) * 8;
    const int frow = lane & 15;
    const int fk   = (lane >> 4) * 8;

    const f16* Ag0 = A  + (size_t)(bm + w*32 +      srow) * 512 + skel;
    const f16* Ag1 = A  + (size_t)(bm + w*32 + 16 + srow) * 512 + skel;
    const f16* Bg0 = Bw + (size_t)(bn + w*32 +      srow) * 512 + skel;
    const f16* Bg1 = Bw + (size_t)(bn + w*32 + 16 + srow) * 512 + skel;

    auto stage = [&](int bsel, int kt) {
        const int k0 = kt << 5;
        char* As_ = smem + bsel*8192;
        char* Bs_ = smem + 24576 + bsel*8192;
        gload16(Ag0 + k0, As_ + (w*32     )*64);
        gload16(Ag1 + k0, As_ + (w*32 + 16)*64);
        gload16(Bg0 + k0, Bs_ + (w*32     )*64);
        gload16(Bg1 + k0, Bs_ + (w*32 + 16)*64);
    };

    f32x4 acc[4][4] = {};

    stage(0, 0);
    stage(1, 1);
    stage(2, 2);

    int buf = 0;
    for (int kt = 0; kt < 16; ++kt) {
        const int rem = 15 - kt;               // tiles allowed in flight
        if (rem >= 2)      asm volatile("s_waitcnt vmcnt(8)" ::: "memory");
        else if (rem == 1) asm volatile("s_waitcnt vmcnt(4)" ::: "memory");
        else               asm volatile("s_waitcnt vmcnt(0)" ::: "memory");
        __builtin_amdgcn_sched_barrier(0);
        __builtin_amdgcn_s_barrier();
        __builtin_amdgcn_sched_barrier(0);

        const char* As_ = smem + buf*8192;
        const char* Bs_ = smem + 24576 + buf*8192;
        f16x8 af[4], bf[4];
        #pragma unroll
        for (int m = 0; m < 4; ++m)
            af[m] = *reinterpret_cast<const f16x8*>(As_ + (wr*64 + m*16 + frow)*64 + fk*2);
        #pragma unroll
        for (int n = 0; n < 4; ++n)
            bf[n] = *reinterpret_cast<const f16x8*>(Bs_ + (wc*64 + n*16 + frow)*64 + fk*2);
        __builtin_amdgcn_sched_barrier(0);
        asm volatile("s_waitcnt lgkmcnt(0)" ::: "memory");
        __builtin_amdgcn_sched_barrier(0);
        __builtin_amdgcn_s_barrier();
        __builtin_amdgcn_sched_barrier(0);

        if (kt + 3 < 16) stage(buf, kt + 3);

        #pragma unroll
        for (int m = 0; m < 4; ++m)
            #pragma unroll
            for (int n = 0; n < 4; ++n)
                acc[m][n] = __builtin_amdgcn_mfma_f32_16x16x32_f16(
                    af[m], bf[n], acc[m][n], 0, 0, 0);
        buf = (buf == 2) ? 0 : buf + 1;
    }

    const int rowb = bm + wr*64 + (lane >> 4) * 4;
    #pragma unroll
    for (int n = 0; n < 4; ++n) {
        const int col = bn + wc*64 + n*16 + frow;
        if (col >= V_) continue;
        const float badd = bias[col];
        #pragma unroll
        for (int m = 0; m < 4; ++m) {
            const int r0 = rowb + m*16;
            #pragma unroll
            for (int r = 0; r < 4; ++r)
                C[(size_t)(r0 + r) * (T_ * V_) + col] = acc[m][n][r] + badd;
        }
    }
}

// ---------------------------------------------------------------------------
// Fused phase kernel: 512 blocks, XCD-aware bn ownership (xcd = bx & 7):
//   [0,128)   L0(p):   bn = (xcd*2 + (i&1))*128, bm = (i>>1)*64
//   [128,256) L1(p-1): same mapping
//   [256,512) OUT(p-2): bn_tile = xcd*8 + (j>>2) (guard <63), bm = (j&3)*128
// Same-XCD blocks own the same weight rows EVERY phase -> L2-resident weights.
// ---------------------------------------------------------------------------
__global__ __launch_bounds__(256)
void phase_kernel(const f16* __restrict__ h0in,   // h0(p-1)
                  const f16* __restrict__ embt,   // emb(p)
                  f16* __restrict__ h0out,        // h0(p)
                  const f16* __restrict__ h1in,   // h1(p-2): L1 input + OUT src
                  f16* __restrict__ h1out,        // h1(p-1)
                  const f16* __restrict__ W0p, const f16* __restrict__ W1p,
                  const f16* __restrict__ WoutP,
                  const float* __restrict__ ctxg,
                  const float* __restrict__ bih1, const float* __restrict__ bhh1,
                  const float* __restrict__ b_out,
                  float* __restrict__ c0, float* __restrict__ c1,
                  float* __restrict__ out, int tout,
                  int active0, int active1, int activeO)
{
    __shared__ char smem[49152];
    const int bx = blockIdx.x;

    if (bx < 128) {
        if (!active0) return;
        const int xcd = bx & 7, idx = bx >> 3;
        const int bn = (xcd*2 + (idx & 1)) * 128;
        const int bm = (idx >> 1) * 64;
        gemm_cell_body(h0in, embt, EW, W0p, 832,
                       ctxg, nullptr, nullptr, c0, h0out, smem, bm, bn);
    } else if (bx < 256) {
        if (!active1) return;
        const int lb = bx - 128;
        const int xcd = lb & 7, idx = lb >> 3;
        const int bn = (xcd*2 + (idx & 1)) * 128;
        const int bm = (idx >> 1) * 64;
        gemm_cell_body(h0in, h1in, 512, W1p, 1024,
                       nullptr, bih1, bhh1, c1, h1out, smem, bm, bn);
    } else {
        if (!activeO) return;
        const int o = bx - 256;                  // 0..255
        const int xcd = o & 7, j = o >> 3;       // j 0..31
        const int bnt = xcd*8 + (j >> 2);        // 0..63
        if (bnt >= 63) return;                   // 4 idle blocks
        const int bm = (j & 3) * 128;
        gemm_out_body(h1in, WoutP, out + (size_t)tout * V_, b_out,
                      bm, bnt * 128, smem, threadIdx.x);
    }
}

// ---------------------------------------------------------------------------
// One-time packs / converts
// ---------------------------------------------------------------------------
__global__ __launch_bounds__(256)
void conv_f16_k(const float* __restrict__ src, f16* __restrict__ dst)
{
    const int i = blockIdx.x * 256 + threadIdx.x;
    const float4 v = reinterpret_cast<const float4*>(src)[i];
    f16x4 h = { (f16)v.x, (f16)v.y, (f16)v.z, (f16)v.w };
    *reinterpret_cast<f16x4*>(dst + (size_t)i * 4) = h;
}

__global__ __launch_bounds__(256)
void pack_wincell(const float* __restrict__ Win, const float* __restrict__ Wcell,
                  f16* __restrict__ dst)
{
    const int i = blockIdx.x * 256 + threadIdx.x;   // 1024*2560/4
    const int r = i / 640, c4 = (i % 640) * 4;
    const float* src = (r < 512) ? Win + (size_t)r * I_ + c4
                                 : Wcell + (size_t)(r - 512) * I_ + c4;
    const float4 v = *reinterpret_cast<const float4*>(src);
    f16x4 h = { (f16)v.x, (f16)v.y, (f16)v.z, (f16)v.w };
    *reinterpret_cast<f16x4*>(dst + (size_t)i * 4) = h;
}

// packed row rp -> (g, h): g = (rp>>5)&3, h = (rp>>7)*32 + (rp&31)
__global__ __launch_bounds__(256)
void pack_w0p(const float* __restrict__ Whh0, const float* __restrict__ Wih0,
              f16* __restrict__ W0)
{
    const int idx = blockIdx.x * 256 + threadIdx.x;   // 2048*832
    const int rp = idx / 832, k = idx % 832;
    const int g = (rp >> 5) & 3, h = (rp >> 7) * 32 + (rp & 31);
    const int srow = g * 512 + h;
    float v;
    if (k < 512)      v = Whh0[(size_t)srow * 512 + k];
    else if (k < 812) v = Wih0[(size_t)srow * 812 + (k - 512)];
    else              v = 0.0f;
    W0[idx] = (f16)v;
}

__global__ __launch_bounds__(256)
void pack_w1p(const float* __restrict__ Wih1, const float* __restrict__ Whh1,
              f16* __restrict__ W1)
{
    const int idx = blockIdx.x * 256 + threadIdx.x;   // 2048*1024
    const int rp = idx >> 10, k = idx & 1023;
    const int g = (rp >> 5) & 3, h = (rp >> 7) * 32 + (rp & 31);
    const int srow = g * 512 + h;
    const float v = (k < 512) ? Wih1[(size_t)srow * 512 + k]
                              : Whh1[(size_t)srow * 512 + (k - 512)];
    W1[idx] = (f16)v;
}

__global__ __launch_bounds__(256)
void pack_wctxp(const float* __restrict__ Wih0, f16* __restrict__ Wc)
{
    const int idx = blockIdx.x * 256 + threadIdx.x;   // 2048*512
    const int rp = idx >> 9, k = idx & 511;
    const int g = (rp >> 5) & 3, h = (rp >> 7) * 32 + (rp & 31);
    Wc[idx] = (f16)Wih0[(size_t)(g * 512 + h) * 812 + 300 + k];
}

__global__ __launch_bounds__(256)
void pack_b0(const float* __restrict__ bih0, const float* __restrict__ bhh0,
             float* __restrict__ b01p)
{
    const int idx = blockIdx.x * 256 + threadIdx.x;   // 2048
    const int g = (idx >> 5) & 3, h = (idx >> 7) * 32 + (idx & 31);
    b01p[idx] = bih0[g * 512 + h] + bhh0[g * 512 + h];
}

__global__ __launch_bounds__(256)
void pack_wout(const float* __restrict__ Wout, f16* __restrict__ Wo)
{
    const int i = blockIdx.x * 256 + threadIdx.x;     // 8064*512/4
    const int r = i >> 7, c4 = (i & 127) * 4;
    f16x4 h = { (f16)0.f, (f16)0.f, (f16)0.f, (f16)0.f };
    if (r < V_) {
        const float4 v = *reinterpret_cast<const float4*>(Wout + (size_t)r * H_ + c4);
        h = f16x4{ (f16)v.x, (f16)v.y, (f16)v.z, (f16)v.w };
    }
    *reinterpret_cast<f16x4*>(Wo + (size_t)i * 4) = h;
}

__global__ __launch_bounds__(256)
void pack_emb_all(const float* __restrict__ emb, const int* __restrict__ target,
                  f16* __restrict__ embAll)
{
    const int idx = blockIdx.x * 256 + threadIdx.x;   // 16*512*320
    const int t = idx / (B_ * EW);
    const int rem = idx % (B_ * EW);
    const int b = rem / EW, e = rem % EW;
    const int wd = (t == 0) ? SOS_ : target[b * T_ + (t - 1)];
    const float v = (e < E_) ? emb[(size_t)wd * E_ + e] : 0.0f;
    embAll[idx] = (f16)v;
}

__global__ __launch_bounds__(256)
void init_state(const float* __restrict__ ctxcc,
                const float* __restrict__ b_in, const float* __restrict__ b_cell,
                f16* __restrict__ ctx16, f16* __restrict__ h0, f16* __restrict__ h1,
                float* __restrict__ c0, float* __restrict__ c1)
{
    const int idx = blockIdx.x * 256 + threadIdx.x;   // 512*512
    const int b = idx >> 9, h = idx & 511;
    const float cv = ctxcc[(size_t)b * 1024 + h] + b_in[h];
    const float cc = ctxcc[(size_t)b * 1024 + 512 + h] + b_cell[h];
    const f16 ch = (f16)cv;
    ctx16[idx] = ch;
    h0[idx] = ch;
    h1[idx] = ch;
    c0[idx] = cc;
    c1[idx] = cc;
}

// ---------------------------------------------------------------------------
extern "C" void kernel_launch(void* const* d_in, const int* in_sizes, int n_in,
                              void* d_out, int out_size, void* d_ws, size_t ws_size,
                              hipStream_t stream)
{
    const float* fused  = (const float*)d_in[0];
    const int*   target = (const int*)d_in[1];
    const float* emb    = (const float*)d_in[3];
    const float* W_in   = (const float*)d_in[4];
    const float* b_in   = (const float*)d_in[5];
    const float* W_cell = (const float*)d_in[6];
    const float* b_cell = (const float*)d_in[7];
    const float* W_ih0  = (const float*)d_in[8];
    const float* W_hh0  = (const float*)d_in[9];
    const float* b_ih0  = (const float*)d_in[10];
    const float* b_hh0  = (const float*)d_in[11];
    const float* W_ih1  = (const float*)d_in[12];
    const float* W_hh1  = (const float*)d_in[13];
    const float* b_ih1  = (const float*)d_in[14];
    const float* b_hh1  = (const float*)d_in[15];
    const float* W_out  = (const float*)d_in[16];
    const float* b_out  = (const float*)d_in[17];
    float* out = (float*)d_out;

    char* p = (char*)d_ws;
    auto carve = [&](size_t bytes) {
        char* r = p;
        p += (bytes + 255) & ~(size_t)255;
        return r;
    };
    float* ctxcc  = (float*)carve((size_t)B_ * 1024 * 4);
    float* ctxg   = (float*)carve((size_t)B_ * G4H * 4);
    float* b01p   = (float*)carve((size_t)G4H * 4);
    float* c0     = (float*)carve((size_t)B_ * H_ * 4);
    float* c1     = (float*)carve((size_t)B_ * H_ * 4);
    f16* fused16  = (f16*)carve((size_t)B_ * I_ * 2);
    f16* WinCell  = (f16*)carve((size_t)1024 * I_ * 2);
    f16* W0p      = (f16*)carve((size_t)G4H * 832 * 2);
    f16* W1p      = (f16*)carve((size_t)G4H * 1024 * 2);
    f16* Wctxp    = (f16*)carve((size_t)G4H * H_ * 2);
    f16* Wout16   = (f16*)carve((size_t)VPAD * H_ * 2);
    f16* ctx16    = (f16*)carve((size_t)B_ * H_ * 2);
    f16* h0a      = (f16*)carve((size_t)B_ * H_ * 2);
    f16* h0b      = (f16*)carve((size_t)B_ * H_ * 2);
    f16* h1a      = (f16*)carve((size_t)B_ * H_ * 2);
    f16* h1b      = (f16*)carve((size_t)B_ * H_ * 2);
    f16* embAll   = (f16*)carve((size_t)T_ * B_ * EW * 2);

    // ---- one-time packs ----
    conv_f16_k  <<<(B_ * I_) / 1024, 256, 0, stream>>>(fused, fused16);
    pack_wincell<<<(1024 * I_) / 1024, 256, 0, stream>>>(W_in, W_cell, WinCell);
    pack_w0p    <<<(G4H * 832) / 256, 256, 0, stream>>>(W_hh0, W_ih0, W0p);
    pack_w1p    <<<(G4H * 1024) / 256, 256, 0, stream>>>(W_ih1, W_hh1, W1p);
    pack_wctxp  <<<(G4H * H_) / 256, 256, 0, stream>>>(W_ih0, Wctxp);
    pack_b0     <<<G4H / 256, 256, 0, stream>>>(b_ih0, b_hh0, b01p);
    pack_wout   <<<(VPAD * H_) / 1024, 256, 0, stream>>>(W_out, Wout16);
    pack_emb_all<<<(T_ * B_ * EW) / 256, 256, 0, stream>>>(emb, target, embAll);

    // ---- ctx / ccell in one GEMM: [512,1024] = fused16 @ [Win|Wcell]^T ----
    gemm_mfma<<<dim3(B_/128, 1024/128), 256, 0, stream>>>(
        fused16, I_, WinCell, I_, ctxcc, 1024, I_, 1024, nullptr, nullptr);

    // h0(-1), h1(-1) live in the parity-1 buffers
    init_state<<<(B_ * H_) / 256, 256, 0, stream>>>(
        ctxcc, b_in, b_cell, ctx16, h0b, h1b, c0, c1);

    // ---- time-invariant ctx gate contribution (packed cols, + b0 biases) ----
    gemm_mfma<<<dim3(B_/128, G4H/128), 256, 0, stream>>>(
        ctx16, H_, Wctxp, H_, ctxg, G4H, H_, G4H, b01p, nullptr);

    // ---- skewed recurrent + fused out-projection: phases 0..17 ----
    // Phase p: L0 -> h0(p); L1 -> h1(p-1); OUT -> logits(t = p-2).
    f16* h0buf[2] = { h0a, h0b };
    f16* h1buf[2] = { h1a, h1b };
    for (int phase = 0; phase <= T_ + 1; ++phase) {
        const int a0 = (phase < T_) ? 1 : 0;
        const int a1 = (phase >= 1 && phase <= T_) ? 1 : 0;
        const int aO = (phase >= 2) ? 1 : 0;
        const int te = (phase < T_) ? phase : (T_ - 1);
        const int tO = aO ? (phase - 2) : 0;
        phase_kernel<<<dim3(512), 256, 0, stream>>>(
            h0buf[(phase + 1) & 1],                 // h0(p-1)
            embAll + (size_t)te * B_ * EW,          // emb(p)
            h0buf[phase & 1],                       // h0(p) out
            h1buf[phase & 1],                       // h1(p-2): L1 input + OUT src
            h1buf[(phase + 1) & 1],                 // h1(p-1) out
            W0p, W1p, Wout16, ctxg, b_ih1, b_hh1, b_out,
            c0, c1, out, tO, a0, a1, aO);
    }
}

// Round 9
// 447.191 us; speedup vs baseline: 3.3278x; 1.0818x over previous
//
#include <hip/hip_runtime.h>
#include <cstdint>

#define B_   512
#define I_   2560
#define H_   512
#define E_   300
#define EW   320     // padded emb width
#define V_   8000
#define VPAD 8064    // 63 * 128
#define T_   16
#define G4H  2048
#define SOS_ 2

typedef _Float16 f16;
typedef _Float16 f16x8 __attribute__((ext_vector_type(8)));
typedef _Float16 f16x4 __attribute__((ext_vector_type(4)));
typedef float    f32x4 __attribute__((ext_vector_type(4)));

__device__ __forceinline__ float sigmoidf_(float x) {
    return 1.0f / (1.0f + __expf(-x));
}

__device__ __forceinline__ void gload16(const void* g, void* l) {
    __builtin_amdgcn_global_load_lds(
        (const __attribute__((address_space(1))) void*)g,
        (__attribute__((address_space(3))) void*)l,
        16, 0, 0);
}

// ---------------------------------------------------------------------------
// Generic MFMA f16 GEMM (m97 structure, verified rounds 2-8) — ctxg GEMM.
// ---------------------------------------------------------------------------
__global__ __launch_bounds__(256)
void gemm_mfma(const f16* __restrict__ A, int lda,
               const f16* __restrict__ Bw, int ldb,
               float* __restrict__ C, int ldc,
               int K, int Nvalid,
               const float* __restrict__ bias1)
{
    __shared__ f16 As[128][32];
    __shared__ f16 Bs[128][32];

    const int tid  = threadIdx.x;
    const int w    = tid >> 6;
    const int lane = tid & 63;
    const int bm   = blockIdx.x * 128;
    const int bn   = blockIdx.y * 128;
    const int wr   = w >> 1;
    const int wc   = w & 1;

    const int srow = lane >> 2;
    const int skel = (lane & 3) * 8;

    const f16* Ag0 = A  + (size_t)(bm + w*32 +      srow) * lda + skel;
    const f16* Ag1 = A  + (size_t)(bm + w*32 + 16 + srow) * lda + skel;
    const f16* Bg0 = Bw + (size_t)(bn + w*32 +      srow) * ldb + skel;
    const f16* Bg1 = Bw + (size_t)(bn + w*32 + 16 + srow) * ldb + skel;
    f16* Al0 = &As[w*32     ][0];
    f16* Al1 = &As[w*32 + 16][0];
    f16* Bl0 = &Bs[w*32     ][0];
    f16* Bl1 = &Bs[w*32 + 16][0];

    const int frow = lane & 15;
    const int fk   = (lane >> 4) * 8;

    f32x4 acc[4][4] = {};

    for (int k0 = 0; k0 < K; k0 += 32) {
        gload16(Ag0 + k0, Al0);
        gload16(Ag1 + k0, Al1);
        gload16(Bg0 + k0, Bl0);
        gload16(Bg1 + k0, Bl1);
        __syncthreads();

        f16x8 af[4], bf[4];
        #pragma unroll
        for (int m = 0; m < 4; ++m)
            af[m] = *reinterpret_cast<const f16x8*>(&As[wr*64 + m*16 + frow][fk]);
        #pragma unroll
        for (int n = 0; n < 4; ++n)
            bf[n] = *reinterpret_cast<const f16x8*>(&Bs[wc*64 + n*16 + frow][fk]);

        #pragma unroll
        for (int m = 0; m < 4; ++m)
            #pragma unroll
            for (int n = 0; n < 4; ++n)
                acc[m][n] = __builtin_amdgcn_mfma_f32_16x16x32_f16(
                    af[m], bf[n], acc[m][n], 0, 0, 0);

        __syncthreads();
    }

    const int rowb = bm + wr*64 + (lane >> 4) * 4;
    #pragma unroll
    for (int n = 0; n < 4; ++n) {
        const int col = bn + wc*64 + n*16 + frow;
        if (col >= Nvalid) continue;
        const float badd = bias1 ? bias1[col] : 0.0f;
        #pragma unroll
        for (int m = 0; m < 4; ++m) {
            const int r0 = rowb + m*16;
            #pragma unroll
            for (int r = 0; r < 4; ++r)
                C[(size_t)(r0 + r) * ldc + col] = acc[m][n][r] + badd;
        }
    }
}

// ---------------------------------------------------------------------------
// ctx/cell-init GEMM: [512,1024] = fused16 @ [Win|Wcell]^T, fused epilogue
// writes ctx16 / h0(-1) / h1(-1) (f16, +b_in) and c0 / c1 (f32, +b_cell).
// ---------------------------------------------------------------------------
__global__ __launch_bounds__(256)
void gemm_ctx_init(const f16* __restrict__ A,        // fused16 [512][2560]
                   const f16* __restrict__ Bw,       // WinCell [1024][2560]
                   const float* __restrict__ b_in,
                   const float* __restrict__ b_cell,
                   f16* __restrict__ ctx16,
                   f16* __restrict__ h0, f16* __restrict__ h1,
                   float* __restrict__ c0, float* __restrict__ c1)
{
    __shared__ f16 As[128][32];
    __shared__ f16 Bs[128][32];

    const int tid  = threadIdx.x;
    const int w    = tid >> 6;
    const int lane = tid & 63;
    const int bm   = blockIdx.x * 128;
    const int bn   = blockIdx.y * 128;
    const int wr   = w >> 1;
    const int wc   = w & 1;

    const int srow = lane >> 2;
    const int skel = (lane & 3) * 8;

    const f16* Ag0 = A  + (size_t)(bm + w*32 +      srow) * I_ + skel;
    const f16* Ag1 = A  + (size_t)(bm + w*32 + 16 + srow) * I_ + skel;
    const f16* Bg0 = Bw + (size_t)(bn + w*32 +      srow) * I_ + skel;
    const f16* Bg1 = Bw + (size_t)(bn + w*32 + 16 + srow) * I_ + skel;
    f16* Al0 = &As[w*32     ][0];
    f16* Al1 = &As[w*32 + 16][0];
    f16* Bl0 = &Bs[w*32     ][0];
    f16* Bl1 = &Bs[w*32 + 16][0];

    const int frow = lane & 15;
    const int fk   = (lane >> 4) * 8;

    f32x4 acc[4][4] = {};

    for (int k0 = 0; k0 < I_; k0 += 32) {
        gload16(Ag0 + k0, Al0);
        gload16(Ag1 + k0, Al1);
        gload16(Bg0 + k0, Bl0);
        gload16(Bg1 + k0, Bl1);
        __syncthreads();

        f16x8 af[4], bf[4];
        #pragma unroll
        for (int m = 0; m < 4; ++m)
            af[m] = *reinterpret_cast<const f16x8*>(&As[wr*64 + m*16 + frow][fk]);
        #pragma unroll
        for (int n = 0; n < 4; ++n)
            bf[n] = *reinterpret_cast<const f16x8*>(&Bs[wc*64 + n*16 + frow][fk]);

        #pragma unroll
        for (int m = 0; m < 4; ++m)
            #pragma unroll
            for (int n = 0; n < 4; ++n)
                acc[m][n] = __builtin_amdgcn_mfma_f32_16x16x32_f16(
                    af[m], bf[n], acc[m][n], 0, 0, 0);

        __syncthreads();
    }

    const int rowb = bm + wr*64 + (lane >> 4) * 4;
    #pragma unroll
    for (int n = 0; n < 4; ++n) {
        const int col = bn + wc*64 + n*16 + frow;
        #pragma unroll
        for (int m = 0; m < 4; ++m) {
            const int r0 = rowb + m*16;
            #pragma unroll
            for (int r = 0; r < 4; ++r) {
                const int row = r0 + r;
                if (col < 512) {
                    const f16 ch = (f16)(acc[m][n][r] + b_in[col]);
                    ctx16[(size_t)row * 512 + col] = ch;
                    h0[(size_t)row * 512 + col] = ch;
                    h1[(size_t)row * 512 + col] = ch;
                } else {
                    const float cc = acc[m][n][r] + b_cell[col - 512];
                    c0[(size_t)row * 512 + col - 512] = cc;
                    c1[(size_t)row * 512 + col - 512] = cc;
                }
            }
        }
    }
}

// ---------------------------------------------------------------------------
// Recurrent GEMM + fused LSTM cell body (round-8 verified, unchanged).
// ---------------------------------------------------------------------------
__device__ __forceinline__ void gemm_cell_body(
    const f16* __restrict__ Ap1, const f16* __restrict__ Ap2, int lda2,
    const f16* __restrict__ Wp, int K,
    const float* __restrict__ Cadd,
    const float* __restrict__ bih, const float* __restrict__ bhh,
    float* __restrict__ cst,
    f16* __restrict__ hout1,
    char* smem, int bm, int bn)
{
    const int tid  = threadIdx.x;
    const int w    = tid >> 6;
    const int lane = tid & 63;
    const int wr   = w >> 1, wc = w & 1;
    const int frow = lane & 15, hi = lane >> 4;
    const int sw   = (frow & 7) << 4;
    const int srow8 = lane >> 3;
    const int ksb  = ((((lane & 7) * 16) ^ (srow8 << 4)) >> 1);

    const int NT = K >> 6;
    f32x4 acc[2][4] = {};

    char* Abuf = smem;            // 2 x 8192
    char* Wbuf = smem + 16384;    // 2 x 16384

    auto stage = [&](int bsel, int kt) {
        const int k0 = kt << 6;
        #pragma unroll
        for (int j = 0; j < 2; ++j) {
            const int row = w*16 + j*8 + srow8;
            const f16* src;
            if (k0 < 512) src = Ap1 + (size_t)(bm + row) * 512  + k0 + ksb;
            else          src = Ap2 + (size_t)(bm + row) * lda2 + (k0 - 512) + ksb;
            gload16(src, Abuf + bsel*8192 + (w*2 + j)*1024 + lane*16);
        }
        #pragma unroll
        for (int j = 0; j < 4; ++j) {
            const int row = w*32 + j*8 + srow8;
            gload16(Wp + (size_t)(bn + row) * K + k0 + ksb,
                    Wbuf + bsel*16384 + (w*4 + j)*1024 + lane*16);
        }
    };

    stage(0, 0);
    stage(1, 1);

    int buf = 0;
    for (int kt = 0; kt < NT; ++kt) {
        if (kt < NT - 1) asm volatile("s_waitcnt vmcnt(6)" ::: "memory");
        else             asm volatile("s_waitcnt vmcnt(0)" ::: "memory");
        __builtin_amdgcn_sched_barrier(0);
        __builtin_amdgcn_s_barrier();
        __builtin_amdgcn_sched_barrier(0);

        const char* A_ = Abuf + buf*8192;
        const char* W_ = Wbuf + buf*16384;
        f16x8 af[2][2], bf[2][4];
        #pragma unroll
        for (int ks = 0; ks < 2; ++ks) {
            const int cb = (ks*64 + hi*16) ^ sw;
            #pragma unroll
            for (int m = 0; m < 2; ++m)
                af[ks][m] = *reinterpret_cast<const f16x8*>(A_ + (wr*32 + m*16 + frow)*128 + cb);
            #pragma unroll
            for (int n = 0; n < 4; ++n)
                bf[ks][n] = *reinterpret_cast<const f16x8*>(W_ + (wc*64 + n*16 + frow)*128 + cb);
        }
        __builtin_amdgcn_sched_barrier(0);
        asm volatile("s_waitcnt lgkmcnt(0)" ::: "memory");
        __builtin_amdgcn_sched_barrier(0);
        __builtin_amdgcn_s_barrier();
        __builtin_amdgcn_sched_barrier(0);

        if (kt + 2 < NT) stage(buf, kt + 2);

        #pragma unroll
        for (int ks = 0; ks < 2; ++ks)
            #pragma unroll
            for (int m = 0; m < 2; ++m)
                #pragma unroll
                for (int n = 0; n < 4; ++n)
                    acc[m][n] = __builtin_amdgcn_mfma_f32_16x16x32_f16(
                        af[ks][m], bf[ks][n], acc[m][n], 0, 0, 0);
        buf ^= 1;
    }

    float* gs = (float*)smem;
    #pragma unroll
    for (int m = 0; m < 2; ++m) {
        const int row = wr*32 + m*16 + hi*4;
        #pragma unroll
        for (int n = 0; n < 4; ++n) {
            const int col = wc*64 + n*16 + frow;
            #pragma unroll
            for (int r = 0; r < 4; ++r) {
                float v = acc[m][n][r];
                if (Cadd) v += Cadd[(size_t)(bm + row + r) * G4H + bn + col];
                gs[(row + r)*132 + col] = v;
            }
        }
    }
    __syncthreads();

    const int hp = tid & 31;
    const int hg = (bn >> 2) + hp;
    float bi0 = 0.f, bi1 = 0.f, bi2 = 0.f, bi3 = 0.f;
    if (bih) {
        bi0 = bih[hg]        + bhh[hg];
        bi1 = bih[512 + hg]  + bhh[512 + hg];
        bi2 = bih[1024 + hg] + bhh[1024 + hg];
        bi3 = bih[1536 + hg] + bhh[1536 + hg];
    }
    #pragma unroll
    for (int i = 0; i < 8; ++i) {
        const int r = (tid >> 5) * 8 + i;
        const int b = bm + r;
        const float gi = gs[r*132 +      hp] + bi0;
        const float gf = gs[r*132 + 32 + hp] + bi1;
        const float gc = gs[r*132 + 64 + hp] + bi2;
        const float go = gs[r*132 + 96 + hp] + bi3;
        const float c  = cst[(size_t)b * 512 + hg];
        const float cn = sigmoidf_(gf) * c + sigmoidf_(gi) * tanhf(gc);
        const float hn = sigmoidf_(go) * tanhf(cn);
        cst[(size_t)b * 512 + hg] = cn;
        hout1[(size_t)b * 512 + hg] = (f16)hn;
    }
}

// ---------------------------------------------------------------------------
// Output-projection tile body, REWRITTEN: BK=64, XOR-swizzled (conflict-free
// ds_read_b128), depth-2 counted vmcnt, 8 K-iterations, nontemporal C stores.
// LDS: A 2x16KB @0, W 2x16KB @32K (64KB total).
// ---------------------------------------------------------------------------
__device__ __forceinline__ void gemm_out_body(
    const f16* __restrict__ A, const f16* __restrict__ Bw,
    float* __restrict__ C,     // = out + t*V_
    const float* __restrict__ bias,
    int bm, int bn, char* smem, int tid)
{
    const int w    = tid >> 6;
    const int lane = tid & 63;
    const int wr   = w >> 1, wc = w & 1;
    const int frow = lane & 15, hi = lane >> 4;
    const int sw   = (frow & 7) << 4;
    const int srow8 = lane >> 3;
    const int ksb  = ((((lane & 7) * 16) ^ (srow8 << 4)) >> 1);

    char* Abuf = smem;            // 2 x 16384
    char* Wbuf = smem + 32768;    // 2 x 16384
    f32x4 acc[4][4] = {};

    auto stage = [&](int bsel, int kt) {
        const int k0 = kt << 6;
        #pragma unroll
        for (int j = 0; j < 4; ++j) {
            const int row = w*32 + j*8 + srow8;
            gload16(A  + (size_t)(bm + row) * 512 + k0 + ksb,
                    Abuf + bsel*16384 + (w*4 + j)*1024 + lane*16);
            gload16(Bw + (size_t)(bn + row) * 512 + k0 + ksb,
                    Wbuf + bsel*16384 + (w*4 + j)*1024 + lane*16);
        }
    };

    stage(0, 0);
    stage(1, 1);

    int buf = 0;
    for (int kt = 0; kt < 8; ++kt) {
        if (kt < 7) asm volatile("s_waitcnt vmcnt(8)" ::: "memory");
        else        asm volatile("s_waitcnt vmcnt(0)" ::: "memory");
        __builtin_amdgcn_sched_barrier(0);
        __builtin_amdgcn_s_barrier();
        __builtin_amdgcn_sched_barrier(0);

        const char* A_ = Abuf + buf*16384;
        const char* W_ = Wbuf + buf*16384;
        f16x8 af[2][4], bf[2][4];
        #pragma unroll
        for (int ks = 0; ks < 2; ++ks) {
            const int cb = (ks*64 + hi*16) ^ sw;
            #pragma unroll
            for (int m = 0; m < 4; ++m)
                af[ks][m] = *reinterpret_cast<const f16x8*>(A_ + (wr*64 + m*16 + frow)*128 + cb);
            #pragma unroll
            for (int n = 0; n < 4; ++n)
                bf[ks][n] = *reinterpret_cast<const f16x8*>(W_ + (wc*64 + n*16 + frow)*128 + cb);
        }
        __builtin_amdgcn_sched_barrier(0);
        asm volatile("s_waitcnt lgkmcnt(0)" ::: "memory");
        __builtin_amdgcn_sched_barrier(0);
        __builtin_amdgcn_s_barrier();
        __builtin_amdgcn_sched_barrier(0);

        if (kt + 2 < 8) stage(buf, kt + 2);

        #pragma unroll
        for (int ks = 0; ks < 2; ++ks)
            #pragma unroll
            for (int m = 0; m < 4; ++m)
                #pragma unroll
                for (int n = 0; n < 4; ++n)
                    acc[m][n] = __builtin_amdgcn_mfma_f32_16x16x32_f16(
                        af[ks][m], bf[ks][n], acc[m][n], 0, 0, 0);
        buf ^= 1;
    }

    const int rowb = bm + wr*64 + (lane >> 4) * 4;
    #pragma unroll
    for (int n = 0; n < 4; ++n) {
        const int col = bn + wc*64 + n*16 + frow;
        if (col >= V_) continue;
        const float badd = bias[col];
        #pragma unroll
        for (int m = 0; m < 4; ++m) {
            const int r0 = rowb + m*16;
            #pragma unroll
            for (int r = 0; r < 4; ++r)
                __builtin_nontemporal_store(
                    acc[m][n][r] + badd,
                    &C[(size_t)(r0 + r) * (T_ * V_) + col]);
        }
    }
}

// ---------------------------------------------------------------------------
// Fused phase kernel (round-8 XCD mapping, 512 blocks).
// ---------------------------------------------------------------------------
__global__ __launch_bounds__(256)
void phase_kernel(const f16* __restrict__ h0in,
                  const f16* __restrict__ embt,
                  f16* __restrict__ h0out,
                  const f16* __restrict__ h1in,
                  f16* __restrict__ h1out,
                  const f16* __restrict__ W0p, const f16* __restrict__ W1p,
                  const f16* __restrict__ WoutP,
                  const float* __restrict__ ctxg,
                  const float* __restrict__ bih1, const float* __restrict__ bhh1,
                  const float* __restrict__ b_out,
                  float* __restrict__ c0, float* __restrict__ c1,
                  float* __restrict__ out, int tout,
                  int active0, int active1, int activeO)
{
    __shared__ char smem[65536];
    const int bx = blockIdx.x;

    if (bx < 128) {
        if (!active0) return;
        const int xcd = bx & 7, idx = bx >> 3;
        const int bn = (xcd*2 + (idx & 1)) * 128;
        const int bm = (idx >> 1) * 64;
        gemm_cell_body(h0in, embt, EW, W0p, 832,
                       ctxg, nullptr, nullptr, c0, h0out, smem, bm, bn);
    } else if (bx < 256) {
        if (!active1) return;
        const int lb = bx - 128;
        const int xcd = lb & 7, idx = lb >> 3;
        const int bn = (xcd*2 + (idx & 1)) * 128;
        const int bm = (idx >> 1) * 64;
        gemm_cell_body(h0in, h1in, 512, W1p, 1024,
                       nullptr, bih1, bhh1, c1, h1out, smem, bm, bn);
    } else {
        if (!activeO) return;
        const int o = bx - 256;                  // 0..255
        const int xcd = o & 7, j = o >> 3;       // j 0..31
        const int bnt = xcd*8 + (j >> 2);        // 0..63
        if (bnt >= 63) return;                   // 4 idle blocks
        const int bm = (j & 3) * 128;
        gemm_out_body(h1in, WoutP, out + (size_t)tout * V_, b_out,
                      bm, bnt * 128, smem, threadIdx.x);
    }
}

// ---------------------------------------------------------------------------
// ONE merged setup kernel: all packs/converts, segmented by block ranges.
// ---------------------------------------------------------------------------
#define NB_F16   1280                 // fused16
#define NB_WIC   2560                 // WinCell
#define NB_W0    6656                 // W0p
#define NB_W1    8192                 // W1p
#define NB_WCTX  4096                 // Wctxp
#define NB_B0    8                    // b01p
#define NB_WOUT  4032                 // Wout16
#define NB_EMB   10240                // embAll
#define NB_TOTAL (NB_F16+NB_WIC+NB_W0+NB_W1+NB_WCTX+NB_B0+NB_WOUT+NB_EMB)

__global__ __launch_bounds__(256)
void pack_all(const float* __restrict__ fused,
              const float* __restrict__ Win, const float* __restrict__ Wcell,
              const float* __restrict__ Whh0, const float* __restrict__ Wih0,
              const float* __restrict__ Wih1, const float* __restrict__ Whh1,
              const float* __restrict__ bih0, const float* __restrict__ bhh0,
              const float* __restrict__ Wout,
              const float* __restrict__ emb, const int* __restrict__ target,
              f16* __restrict__ fused16, f16* __restrict__ WinCell,
              f16* __restrict__ W0, f16* __restrict__ W1,
              f16* __restrict__ Wc, float* __restrict__ b01p,
              f16* __restrict__ Wo, f16* __restrict__ embAll)
{
    int bx = blockIdx.x;
    const int tid = threadIdx.x;

    if (bx < NB_F16) {
        const int i = bx * 256 + tid;
        const float4 v = reinterpret_cast<const float4*>(fused)[i];
        f16x4 h = { (f16)v.x, (f16)v.y, (f16)v.z, (f16)v.w };
        *reinterpret_cast<f16x4*>(fused16 + (size_t)i * 4) = h;
        return;
    }
    bx -= NB_F16;
    if (bx < NB_WIC) {
        const int i = bx * 256 + tid;
        const int r = i / 640, c4 = (i % 640) * 4;
        const float* src = (r < 512) ? Win + (size_t)r * I_ + c4
                                     : Wcell + (size_t)(r - 512) * I_ + c4;
        const float4 v = *reinterpret_cast<const float4*>(src);
        f16x4 h = { (f16)v.x, (f16)v.y, (f16)v.z, (f16)v.w };
        *reinterpret_cast<f16x4*>(WinCell + (size_t)i * 4) = h;
        return;
    }
    bx -= NB_WIC;
    if (bx < NB_W0) {
        const int idx = bx * 256 + tid;
        const int rp = idx / 832, k = idx % 832;
        const int g = (rp >> 5) & 3, h = (rp >> 7) * 32 + (rp & 31);
        const int srow = g * 512 + h;
        float v;
        if (k < 512)      v = Whh0[(size_t)srow * 512 + k];
        else if (k < 812) v = Wih0[(size_t)srow * 812 + (k - 512)];
        else              v = 0.0f;
        W0[idx] = (f16)v;
        return;
    }
    bx -= NB_W0;
    if (bx < NB_W1) {
        const int idx = bx * 256 + tid;
        const int rp = idx >> 10, k = idx & 1023;
        const int g = (rp >> 5) & 3, h = (rp >> 7) * 32 + (rp & 31);
        const int srow = g * 512 + h;
        const float v = (k < 512) ? Wih1[(size_t)srow * 512 + k]
                                  : Whh1[(size_t)srow * 512 + (k - 512)];
        W1[idx] = (f16)v;
        return;
    }
    bx -= NB_W1;
    if (bx < NB_WCTX) {
        const int idx = bx * 256 + tid;
        const int rp = idx >> 9, k = idx & 511;
        const int g = (rp >> 5) & 3, h = (rp >> 7) * 32 + (rp & 31);
        Wc[idx] = (f16)Wih0[(size_t)(g * 512 + h) * 812 + 300 + k];
        return;
    }
    bx -= NB_WCTX;
    if (bx < NB_B0) {
        const int idx = bx * 256 + tid;
        const int g = (idx >> 5) & 3, h = (idx >> 7) * 32 + (idx & 31);
        b01p[idx] = bih0[g * 512 + h] + bhh0[g * 512 + h];
        return;
    }
    bx -= NB_B0;
    if (bx < NB_WOUT) {
        const int i = bx * 256 + tid;
        const int r = i >> 7, c4 = (i & 127) * 4;
        f16x4 h = { (f16)0.f, (f16)0.f, (f16)0.f, (f16)0.f };
        if (r < V_) {
            const float4 v = *reinterpret_cast<const float4*>(Wout + (size_t)r * H_ + c4);
            h = f16x4{ (f16)v.x, (f16)v.y, (f16)v.z, (f16)v.w };
        }
        *reinterpret_cast<f16x4*>(Wo + (size_t)i * 4) = h;
        return;
    }
    bx -= NB_WOUT;
    {
        const int idx = bx * 256 + tid;
        const int t = idx / (B_ * EW);
        const int rem = idx % (B_ * EW);
        const int b = rem / EW, e = rem % EW;
        const int wd = (t == 0) ? SOS_ : target[b * T_ + (t - 1)];
        const float v = (e < E_) ? emb[(size_t)wd * E_ + e] : 0.0f;
        embAll[idx] = (f16)v;
    }
}

// ---------------------------------------------------------------------------
extern "C" void kernel_launch(void* const* d_in, const int* in_sizes, int n_in,
                              void* d_out, int out_size, void* d_ws, size_t ws_size,
                              hipStream_t stream)
{
    const float* fused  = (const float*)d_in[0];
    const int*   target = (const int*)d_in[1];
    const float* emb    = (const float*)d_in[3];
    const float* W_in   = (const float*)d_in[4];
    const float* b_in   = (const float*)d_in[5];
    const float* W_cell = (const float*)d_in[6];
    const float* b_cell = (const float*)d_in[7];
    const float* W_ih0  = (const float*)d_in[8];
    const float* W_hh0  = (const float*)d_in[9];
    const float* b_ih0  = (const float*)d_in[10];
    const float* b_hh0  = (const float*)d_in[11];
    const float* W_ih1  = (const float*)d_in[12];
    const float* W_hh1  = (const float*)d_in[13];
    const float* b_ih1  = (const float*)d_in[14];
    const float* b_hh1  = (const float*)d_in[15];
    const float* W_out  = (const float*)d_in[16];
    const float* b_out  = (const float*)d_in[17];
    float* out = (float*)d_out;

    char* p = (char*)d_ws;
    auto carve = [&](size_t bytes) {
        char* r = p;
        p += (bytes + 255) & ~(size_t)255;
        return r;
    };
    float* ctxg   = (float*)carve((size_t)B_ * G4H * 4);
    float* b01p   = (float*)carve((size_t)G4H * 4);
    float* c0     = (float*)carve((size_t)B_ * H_ * 4);
    float* c1     = (float*)carve((size_t)B_ * H_ * 4);
    f16* fused16  = (f16*)carve((size_t)B_ * I_ * 2);
    f16* WinCell  = (f16*)carve((size_t)1024 * I_ * 2);
    f16* W0p      = (f16*)carve((size_t)G4H * 832 * 2);
    f16* W1p      = (f16*)carve((size_t)G4H * 1024 * 2);
    f16* Wctxp    = (f16*)carve((size_t)G4H * H_ * 2);
    f16* Wout16   = (f16*)carve((size_t)VPAD * H_ * 2);
    f16* ctx16    = (f16*)carve((size_t)B_ * H_ * 2);
    f16* h0a      = (f16*)carve((size_t)B_ * H_ * 2);
    f16* h0b      = (f16*)carve((size_t)B_ * H_ * 2);
    f16* h1a      = (f16*)carve((size_t)B_ * H_ * 2);
    f16* h1b      = (f16*)carve((size_t)B_ * H_ * 2);
    f16* embAll   = (f16*)carve((size_t)T_ * B_ * EW * 2);

    // ---- 1 merged pack launch ----
    pack_all<<<dim3(NB_TOTAL), 256, 0, stream>>>(
        fused, W_in, W_cell, W_hh0, W_ih0, W_ih1, W_hh1,
        b_ih0, b_hh0, W_out, emb, target,
        fused16, WinCell, W0p, W1p, Wctxp, b01p, Wout16, embAll);

    // ---- ctx/cell-init GEMM with fused init epilogue ----
    gemm_ctx_init<<<dim3(B_/128, 1024/128), 256, 0, stream>>>(
        fused16, WinCell, b_in, b_cell, ctx16, h0b, h1b, c0, c1);

    // ---- time-invariant ctx gate contribution (+ b0 biases) ----
    gemm_mfma<<<dim3(B_/128, G4H/128), 256, 0, stream>>>(
        ctx16, H_, Wctxp, H_, ctxg, G4H, H_, G4H, b01p);

    // ---- skewed recurrent + fused out-projection: phases 0..17 ----
    f16* h0buf[2] = { h0a, h0b };
    f16* h1buf[2] = { h1a, h1b };
    for (int phase = 0; phase <= T_ + 1; ++phase) {
        const int a0 = (phase < T_) ? 1 : 0;
        const int a1 = (phase >= 1 && phase <= T_) ? 1 : 0;
        const int aO = (phase >= 2) ? 1 : 0;
        const int te = (phase < T_) ? phase : (T_ - 1);
        const int tO = aO ? (phase - 2) : 0;
        phase_kernel<<<dim3(512), 256, 0, stream>>>(
            h0buf[(phase + 1) & 1],
            embAll + (size_t)te * B_ * EW,
            h0buf[phase & 1],
            h1buf[phase & 1],
            h1buf[(phase + 1) & 1],
            W0p, W1p, Wout16, ctxg, b_ih1, b_hh1, b_out,
            c0, c1, out, tO, a0, a1, aO);
    }
}